// Round 1
// baseline (678.505 us; speedup 1.0000x reference)
//
#include <hip/hip_runtime.h>

#define EPSV 1e-5f

// ---------------------------------------------------------------------------
// Stage 1 / Stage 4: 1x1 conv as GEMM  C[Co x (B*4096)] = W[Co x Ci] * X
// Tile 64x64, BK=16, 256 threads, 4x4 micro-tile. BN (+optional residual) + ReLU epilogue.
// ---------------------------------------------------------------------------
template<bool RESID>
__global__ __launch_bounds__(256) void conv1x1_bn_act(
    const float* __restrict__ in,    // [B, Ci, 4096]
    const float* __restrict__ wt,    // [Co, Ci]
    const float* __restrict__ g, const float* __restrict__ bb,
    const float* __restrict__ m, const float* __restrict__ v,
    const float* __restrict__ resid, // [B, Co, 4096] or null
    float* __restrict__ out,         // [B, Co, 4096]
    int Ci, int Co)
{
    __shared__ float As[16][68];   // [k][m], stride 68 keeps rows 16B-aligned
    __shared__ float Bs[16][64];   // [k][n]

    const int tid  = threadIdx.x;
    const int colt = blockIdx.x;          // 0..127  (64 col-tiles per batch)
    const int cot  = blockIdx.y;          // Co/64
    const int b    = colt >> 6;
    const int hw0  = (colt & 63) << 6;
    const int co0  = cot << 6;
    const int tx   = tid & 15, ty = tid >> 4;

    float acc[4][4] = {};

    // A load: thread -> float4 at row am (0..63), k offset ak
    const int am = tid >> 2, ak = (tid & 3) << 2;
    // B load: thread -> float4 at k row bk (0..15), col offset bn
    const int bk = tid >> 4, bn = (tid & 15) << 2;

    const float* aPtr = wt + (size_t)(co0 + am) * Ci + ak;
    const float* bPtr = in + ((size_t)b * Ci << 12) + ((size_t)bk << 12) + hw0 + bn;

    const int kIters = Ci >> 4;
    for (int kt = 0; kt < kIters; ++kt) {
        float4 av = *(const float4*)(aPtr + (kt << 4));
        float4 bv = *(const float4*)(bPtr + (((size_t)kt << 4) << 12));
        As[ak + 0][am] = av.x;
        As[ak + 1][am] = av.y;
        As[ak + 2][am] = av.z;
        As[ak + 3][am] = av.w;
        *(float4*)&Bs[bk][bn] = bv;
        __syncthreads();
#pragma unroll
        for (int k = 0; k < 16; ++k) {
            float a0[4], b0[4];
#pragma unroll
            for (int i = 0; i < 4; i++) a0[i] = As[k][ty * 4 + i];
#pragma unroll
            for (int j = 0; j < 4; j++) b0[j] = Bs[k][tx * 4 + j];
#pragma unroll
            for (int i = 0; i < 4; i++)
#pragma unroll
                for (int j = 0; j < 4; j++) acc[i][j] += a0[i] * b0[j];
        }
        __syncthreads();
    }

#pragma unroll
    for (int i = 0; i < 4; i++) {
        const int co = co0 + ty * 4 + i;
        const float s = g[co] * rsqrtf(v[co] + EPSV);
        const float t = bb[co] - m[co] * s;
        const size_t base = (((size_t)b * Co + co) << 12) + hw0 + tx * 4;
        float* dst = out + base;
#pragma unroll
        for (int j = 0; j < 4; j++) {
            float val = acc[i][j] * s + t;
            if (RESID) val += resid[base + j];
            dst[j] = val > 0.f ? val : 0.f;
        }
    }
}

// ---------------------------------------------------------------------------
// Stage 2: 3x3 conv producing 18 offset channels. One wave per (b,o,h) row.
// ---------------------------------------------------------------------------
__global__ __launch_bounds__(64) void offset_conv3x3(
    const float* __restrict__ out1,   // [2,256,64,64]
    const float* __restrict__ w_off,  // [18,256,3,3]
    const float* __restrict__ b_off,  // [18]
    float* __restrict__ offs)         // [2,18,64,64]
{
    const int h = blockIdx.x;   // 64
    const int o = blockIdx.y;   // 18
    const int b = blockIdx.z;   // 2
    const int w = threadIdx.x;  // 64

    float acc = b_off[o];
    for (int c = 0; c < 256; ++c) {
        const float* plane = out1 + (((size_t)(b * 256 + c)) << 12);
        const float* wk    = w_off + ((size_t)(o * 256 + c)) * 9;
#pragma unroll
        for (int ky = 0; ky < 3; ++ky) {
            const int y = h + ky - 1;
            if (y < 0 || y > 63) continue;
            const float* row = plane + (y << 6);
#pragma unroll
            for (int kx = 0; kx < 3; ++kx) {
                const int x = w + kx - 1;
                const float xv = (x >= 0 && x <= 63) ? row[x] : 0.f;
                acc += xv * wk[ky * 3 + kx];
            }
        }
    }
    offs[(((size_t)(b * 18 + o)) << 12) + (h << 6) + w] = acc;
}

// ---------------------------------------------------------------------------
// Stage 3: deformable 3x3 conv + BN + ReLU.
// Block = (h-row, b, o-group of 64). 256 threads.
// Phase A: precompute per-sample geometry (4 clipped corner offsets + 4
//          validity-folded bilinear weights) for 9k x 64w points into LDS.
// Phase B: loop c in batches of 4; cooperative bilinear sampling into LDS,
//          then each thread accumulates 4 o x 4 w from broadcast LDS reads.
// ---------------------------------------------------------------------------
__global__ __launch_bounds__(256) void deform_conv_bn_relu(
    const float* __restrict__ out1,  // [2,256,64,64]
    const float* __restrict__ offs,  // [2,18,64,64]
    const float* __restrict__ w2,    // [256,256,3,3]
    const float* __restrict__ g2, const float* __restrict__ b2,
    const float* __restrict__ m2, const float* __restrict__ v2,
    float* __restrict__ out2)        // [2,256,64,64]
{
    const int h   = blockIdx.x;   // 0..63
    const int b   = blockIdx.y;   // 0..1
    const int og  = blockIdx.z;   // 0..3
    const int tid = threadIdx.x;

    __shared__ int   s_off[4][576];   // [corner][k*64+w]
    __shared__ float s_wt [4][576];
    __shared__ float s_val[4][576];   // [cc][k*64+w]

    // ---- Phase A: geometry ----
    for (int p = tid; p < 576; p += 256) {
        const int k = p >> 6;
        const int w = p & 63;
        const float dy = offs[(((size_t)(b * 18 + 2 * k)) << 12) + (h << 6) + w];
        const float dx = offs[(((size_t)(b * 18 + 2 * k + 1)) << 12) + (h << 6) + w];
        const float py = (float)h + (float)(k / 3 - 1) + dy;
        const float px = (float)w + (float)(k % 3 - 1) + dx;
        const float y0f = floorf(py), x0f = floorf(px);
        const int y0 = (int)y0f, x0 = (int)x0f;
        const float wy1 = py - y0f, wx1 = px - x0f;
        const float wy0 = 1.f - wy1, wx0 = 1.f - wx1;
        const int y1 = y0 + 1, x1 = x0 + 1;
        const bool vy0 = (y0 >= 0) && (y0 < 64);
        const bool vy1 = (y1 >= 0) && (y1 < 64);
        const bool vx0 = (x0 >= 0) && (x0 < 64);
        const bool vx1 = (x1 >= 0) && (x1 < 64);
        const int cy0 = min(max(y0, 0), 63), cy1 = min(max(y1, 0), 63);
        const int cx0 = min(max(x0, 0), 63), cx1 = min(max(x1, 0), 63);
        s_off[0][p] = (cy0 << 6) + cx0;  s_wt[0][p] = wy0 * wx0 * ((vy0 && vx0) ? 1.f : 0.f);
        s_off[1][p] = (cy0 << 6) + cx1;  s_wt[1][p] = wy0 * wx1 * ((vy0 && vx1) ? 1.f : 0.f);
        s_off[2][p] = (cy1 << 6) + cx0;  s_wt[2][p] = wy1 * wx0 * ((vy1 && vx0) ? 1.f : 0.f);
        s_off[3][p] = (cy1 << 6) + cx1;  s_wt[3][p] = wy1 * wx1 * ((vy1 && vx1) ? 1.f : 0.f);
    }
    __syncthreads();

    const int obase = (og << 6) + ((tid >> 4) << 2);  // 4 consecutive o
    const int w0    = (tid & 15) << 2;                // 4 consecutive w
    float acc[4][4] = {};

    // ---- Phase B: channel batches of 4 ----
    for (int cb = 0; cb < 64; ++cb) {
        const int c0 = cb << 2;
        for (int i = tid; i < 4 * 576; i += 256) {
            const int cc = i / 576;
            const int p  = i - cc * 576;
            const float* plane = out1 + (((size_t)((b << 8) + c0 + cc)) << 12);
            const float val = s_wt[0][p] * plane[s_off[0][p]]
                            + s_wt[1][p] * plane[s_off[1][p]]
                            + s_wt[2][p] * plane[s_off[2][p]]
                            + s_wt[3][p] * plane[s_off[3][p]];
            s_val[cc][p] = val;
        }
        __syncthreads();

#pragma unroll
        for (int cc = 0; cc < 4; ++cc) {
            float wv[4][9];
#pragma unroll
            for (int i = 0; i < 4; i++) {
                const float* wr = w2 + ((size_t)((obase + i) * 256 + c0 + cc)) * 9;
#pragma unroll
                for (int k = 0; k < 9; k++) wv[i][k] = wr[k];
            }
#pragma unroll
            for (int k = 0; k < 9; k++) {
                const float* sv = &s_val[cc][(k << 6) + w0];
                float s0 = sv[0], s1 = sv[1], s2 = sv[2], s3 = sv[3];
#pragma unroll
                for (int i = 0; i < 4; i++) {
                    acc[i][0] += s0 * wv[i][k];
                    acc[i][1] += s1 * wv[i][k];
                    acc[i][2] += s2 * wv[i][k];
                    acc[i][3] += s3 * wv[i][k];
                }
            }
        }
        __syncthreads();
    }

    // ---- epilogue: BN + ReLU ----
#pragma unroll
    for (int i = 0; i < 4; i++) {
        const int o = obase + i;
        const float s = g2[o] * rsqrtf(v2[o] + EPSV);
        const float t = b2[o] - m2[o] * s;
        float* dst = out2 + (((size_t)((b << 8) + o)) << 12) + (h << 6) + w0;
#pragma unroll
        for (int j = 0; j < 4; j++) {
            const float val = acc[i][j] * s + t;
            dst[j] = val > 0.f ? val : 0.f;
        }
    }
}

// ---------------------------------------------------------------------------
extern "C" void kernel_launch(void* const* d_in, const int* in_sizes, int n_in,
                              void* d_out, int out_size, void* d_ws, size_t ws_size,
                              hipStream_t stream) {
    const float* x     = (const float*)d_in[0];
    const float* w1    = (const float*)d_in[1];
    const float* g1    = (const float*)d_in[2];
    const float* b1    = (const float*)d_in[3];
    const float* m1    = (const float*)d_in[4];
    const float* v1    = (const float*)d_in[5];
    const float* w_off = (const float*)d_in[6];
    const float* b_off = (const float*)d_in[7];
    const float* w2    = (const float*)d_in[8];
    const float* g2    = (const float*)d_in[9];
    const float* b2    = (const float*)d_in[10];
    const float* m2    = (const float*)d_in[11];
    const float* v2    = (const float*)d_in[12];
    const float* w3    = (const float*)d_in[13];
    const float* g3    = (const float*)d_in[14];
    const float* b3    = (const float*)d_in[15];
    const float* m3    = (const float*)d_in[16];
    const float* v3    = (const float*)d_in[17];
    float* out = (float*)d_out;

    float* out1 = (float*)d_ws;                  // 2*256*4096 = 2,097,152 f32
    float* offs = out1 + (size_t)2 * 256 * 4096; // 2*18*4096  =   147,456 f32
    float* out2 = offs + (size_t)2 * 18 * 4096;  // 2*256*4096 = 2,097,152 f32

    // Stage 1: conv1x1(x, w1) + BN1 + ReLU -> out1
    conv1x1_bn_act<false><<<dim3(128, 4), 256, 0, stream>>>(
        x, w1, g1, b1, m1, v1, nullptr, out1, 1024, 256);

    // Stage 2: conv3x3(out1, w_off) + b_off -> offs
    offset_conv3x3<<<dim3(64, 18, 2), 64, 0, stream>>>(out1, w_off, b_off, offs);

    // Stage 3: deform_conv3x3(out1, offs, w2) + BN2 + ReLU -> out2
    deform_conv_bn_relu<<<dim3(64, 2, 4), 256, 0, stream>>>(
        out1, offs, w2, g2, b2, m2, v2, out2);

    // Stage 4: conv1x1(out2, w3) + BN3 + residual(x) + ReLU -> out
    conv1x1_bn_act<true><<<dim3(128, 16), 256, 0, stream>>>(
        out2, w3, g3, b3, m3, v3, x, out, 256, 1024);
}

// Round 2
// 494.126 us; speedup vs baseline: 1.3731x; 1.3731x over previous
//
#include <hip/hip_runtime.h>
#include <hip/hip_bf16.h>

#define EPSV 1e-5f

typedef __attribute__((ext_vector_type(4))) float f32x4;
typedef __attribute__((ext_vector_type(8))) short bf16x8;
typedef unsigned short u16;
typedef unsigned int u32;

#define AS1(p) ((const __attribute__((address_space(1))) void*)(p))
#define AS3(p) ((__attribute__((address_space(3))) void*)(p))

__device__ __forceinline__ float bf2f(u16 u) {
    union { u32 i; float f; } x; x.i = ((u32)u) << 16; return x.f;
}
__device__ __forceinline__ u16 f2bf(float f) {
    __hip_bfloat16 h = __float2bfloat16(f);
    return *reinterpret_cast<u16*>(&h);
}

// ---------------------------------------------------------------------------
// fp32 -> bf16 elementwise (weights). n4 = n/4.
// ---------------------------------------------------------------------------
__global__ __launch_bounds__(256) void cvt_w(const float* __restrict__ in,
                                             u16* __restrict__ out, int n4) {
    int i = blockIdx.x * 256 + threadIdx.x;
    if (i < n4) {
        float4 v = ((const float4*)in)[i];
        ushort4 o;
        o.x = f2bf(v.x); o.y = f2bf(v.y); o.z = f2bf(v.z); o.w = f2bf(v.w);
        ((ushort4*)out)[i] = o;
    }
}

// ---------------------------------------------------------------------------
// x [2][1024][4096] fp32  ->  xbT [8192][1024] bf16   (n = b*4096+hw)
// 64c x 64hw tile transpose via LDS.
// ---------------------------------------------------------------------------
__global__ __launch_bounds__(256) void cvt_x_T(const float* __restrict__ x,
                                               u16* __restrict__ xbT) {
    __shared__ u16 tile[64][72];   // row stride 144B (16B-aligned)
    const int tid = threadIdx.x;
    const int hw0 = blockIdx.x << 6;
    const int c0  = blockIdx.y << 6;
    const int b   = blockIdx.z;
    const int cl  = tid >> 4;         // 0..15
    const int hwl = (tid & 15) << 2;  // 0..60
#pragma unroll
    for (int i = 0; i < 4; i++) {
        const int c = cl + i * 16;
        float4 v = *(const float4*)(x + (((size_t)(b * 1024 + c0 + c)) << 12) + hw0 + hwl);
        tile[hwl + 0][c] = f2bf(v.x);
        tile[hwl + 1][c] = f2bf(v.y);
        tile[hwl + 2][c] = f2bf(v.z);
        tile[hwl + 3][c] = f2bf(v.w);
    }
    __syncthreads();
    const int hw  = tid >> 2;
    const int seg = tid & 3;
    u16* dst = xbT + ((size_t)(b * 4096 + hw0 + hw)) * 1024 + c0 + seg * 16;
    const u16* src = &tile[hw][seg * 16];
#pragma unroll
    for (int q = 0; q < 2; q++)
        *(uint4*)(dst + q * 8) = *(const uint4*)(src + q * 8);
}

// ---------------------------------------------------------------------------
// Templated MFMA GEMM: D[M x 8192] = A[M x K] * B[K x 8192], B given as
// BT[n][k] (k-contiguous). Tile 64x128, BK=32, 256 threads (4 waves 2x2,
// wave tile 32x64). global_load_lds width-16 staging, 2-barrier loop.
// MODE 0: BN+ReLU -> bf16 out[M][8192]
// MODE 1: BN+ReLU -> bf16 outT[8192][M] (LDS transpose epilogue)
// MODE 2: BN + resid + ReLU -> fp32 out [2][M][4096] (n=b*4096+hw)
// ---------------------------------------------------------------------------
template<int MODE>
__global__ __launch_bounds__(256) void gemm_bn(
    const u16* __restrict__ A, const u16* __restrict__ BT,
    const float* __restrict__ g, const float* __restrict__ bb,
    const float* __restrict__ m, const float* __restrict__ v,
    const float* __restrict__ resid, void* __restrict__ out, int K)
{
    extern __shared__ char sm[];
    u16* As = (u16*)sm;            // [64][32]
    u16* Bs = (u16*)(sm + 4096);   // [128][32]

    const int tid  = threadIdx.x;
    const int lane = tid & 63;
    const int wid  = tid >> 6;
    const int n0 = blockIdx.x << 7;
    const int m0 = blockIdx.y << 6;
    const int wr = wid >> 1, wc = wid & 1;
    const int lr = lane & 15, kg = lane >> 4;

    f32x4 acc[2][4] = {};

    const int arow = tid >> 2, aseg = (tid & 3) << 3;   // element offset
    const u16* aG  = A  + (size_t)(m0 + arow) * K + aseg;
    const u16* bG0 = BT + (size_t)(n0 + arow) * K + aseg;
    const u16* bG1 = BT + (size_t)(n0 + 64 + arow) * K + aseg;
    char* ldsA  = ((char*)As) + wid * 1024;
    char* ldsB0 = ((char*)Bs) + wid * 1024;
    char* ldsB1 = ((char*)Bs) + 4096 + wid * 1024;

    const u16* Asp = As + (wr * 32 + lr) * 32 + kg * 8;
    const u16* Bsp = Bs + (wc * 64 + lr) * 32 + kg * 8;

    for (int kt = 0; kt < K; kt += 32) {
        __builtin_amdgcn_global_load_lds(AS1(aG  + kt), AS3(ldsA),  16, 0, 0);
        __builtin_amdgcn_global_load_lds(AS1(bG0 + kt), AS3(ldsB0), 16, 0, 0);
        __builtin_amdgcn_global_load_lds(AS1(bG1 + kt), AS3(ldsB1), 16, 0, 0);
        __syncthreads();
        bf16x8 a0 = *(const bf16x8*)(Asp);
        bf16x8 a1 = *(const bf16x8*)(Asp + 512);
        bf16x8 b0 = *(const bf16x8*)(Bsp);
        bf16x8 b1 = *(const bf16x8*)(Bsp + 512);
        bf16x8 b2 = *(const bf16x8*)(Bsp + 1024);
        bf16x8 b3 = *(const bf16x8*)(Bsp + 1536);
        acc[0][0] = __builtin_amdgcn_mfma_f32_16x16x32_bf16(a0, b0, acc[0][0], 0, 0, 0);
        acc[0][1] = __builtin_amdgcn_mfma_f32_16x16x32_bf16(a0, b1, acc[0][1], 0, 0, 0);
        acc[0][2] = __builtin_amdgcn_mfma_f32_16x16x32_bf16(a0, b2, acc[0][2], 0, 0, 0);
        acc[0][3] = __builtin_amdgcn_mfma_f32_16x16x32_bf16(a0, b3, acc[0][3], 0, 0, 0);
        acc[1][0] = __builtin_amdgcn_mfma_f32_16x16x32_bf16(a1, b0, acc[1][0], 0, 0, 0);
        acc[1][1] = __builtin_amdgcn_mfma_f32_16x16x32_bf16(a1, b1, acc[1][1], 0, 0, 0);
        acc[1][2] = __builtin_amdgcn_mfma_f32_16x16x32_bf16(a1, b2, acc[1][2], 0, 0, 0);
        acc[1][3] = __builtin_amdgcn_mfma_f32_16x16x32_bf16(a1, b3, acc[1][3], 0, 0, 0);
        __syncthreads();
    }

    // BN coefficients per (mm, r): o = m0 + wr*32 + mm*16 + kg*4 + r
    float sc[2][4], tc[2][4];
#pragma unroll
    for (int mm = 0; mm < 2; mm++)
#pragma unroll
        for (int r = 0; r < 4; r++) {
            const int o = m0 + wr * 32 + mm * 16 + kg * 4 + r;
            const float s = g[o] * rsqrtf(v[o] + EPSV);
            sc[mm][r] = s;
            tc[mm][r] = bb[o] - m[o] * s;
        }

    if (MODE == 0) {
        u16* O = (u16*)out;
#pragma unroll
        for (int mm = 0; mm < 2; mm++)
#pragma unroll
            for (int r = 0; r < 4; r++) {
                const int o = m0 + wr * 32 + mm * 16 + kg * 4 + r;
#pragma unroll
                for (int j = 0; j < 4; j++) {
                    const int n = n0 + wc * 64 + j * 16 + lr;
                    float val = acc[mm][j][r] * sc[mm][r] + tc[mm][r];
                    val = val > 0.f ? val : 0.f;
                    O[(size_t)o * 8192 + n] = f2bf(val);
                }
            }
    } else if (MODE == 1) {
        u16* T = (u16*)(sm + 12288);   // [128][72]
#pragma unroll
        for (int mm = 0; mm < 2; mm++) {
            const int ol = wr * 32 + mm * 16 + kg * 4;
#pragma unroll
            for (int j = 0; j < 4; j++) {
                const int nl = wc * 64 + j * 16 + lr;
                float v0 = acc[mm][j][0] * sc[mm][0] + tc[mm][0];
                float v1 = acc[mm][j][1] * sc[mm][1] + tc[mm][1];
                float v2 = acc[mm][j][2] * sc[mm][2] + tc[mm][2];
                float v3 = acc[mm][j][3] * sc[mm][3] + tc[mm][3];
                v0 = v0 > 0.f ? v0 : 0.f; v1 = v1 > 0.f ? v1 : 0.f;
                v2 = v2 > 0.f ? v2 : 0.f; v3 = v3 > 0.f ? v3 : 0.f;
                u32 p01 = (u32)f2bf(v0) | ((u32)f2bf(v1) << 16);
                u32 p23 = (u32)f2bf(v2) | ((u32)f2bf(v3) << 16);
                *(u32*)&T[nl * 72 + ol]     = p01;
                *(u32*)&T[nl * 72 + ol + 2] = p23;
            }
        }
        __syncthreads();
        const int nl = tid >> 1, half = tid & 1;
        u16* dst = (u16*)out + (size_t)(n0 + nl) * 256 + m0 + half * 32;
        const u16* src = &T[nl * 72 + half * 32];
#pragma unroll
        for (int q = 0; q < 4; q++)
            *(uint4*)(dst + q * 8) = *(const uint4*)(src + q * 8);
    } else {
        float* O = (float*)out;
#pragma unroll
        for (int mm = 0; mm < 2; mm++)
#pragma unroll
            for (int r = 0; r < 4; r++) {
                const int o = m0 + wr * 32 + mm * 16 + kg * 4 + r;
#pragma unroll
                for (int j = 0; j < 4; j++) {
                    const int n = n0 + wc * 64 + j * 16 + lr;
                    const size_t idx = ((size_t)(n >> 12) << 22) + ((size_t)o << 12) + (n & 4095);
                    float val = acc[mm][j][r] * sc[mm][r] + tc[mm][r] + resid[idx];
                    O[idx] = val > 0.f ? val : 0.f;
                }
            }
    }
}

// ---------------------------------------------------------------------------
// Offset conv 3x3 (18 ch), bf16 input, fp32 math/out. One wave per (b,o,h).
// ---------------------------------------------------------------------------
__global__ __launch_bounds__(64) void offset_conv(
    const u16* __restrict__ out1,     // [256][8192] bf16, n = b*4096+hw
    const float* __restrict__ w_off,  // [18][256][3][3]
    const float* __restrict__ b_off,
    float* __restrict__ offs)         // [2][18][4096]
{
    const int h = blockIdx.x, o = blockIdx.y, b = blockIdx.z;
    const int w = threadIdx.x;
    float acc = b_off[o];
    for (int c = 0; c < 256; ++c) {
        const u16* plane = out1 + (size_t)c * 8192 + b * 4096;
        const float* wk = w_off + ((size_t)(o * 256 + c)) * 9;
#pragma unroll
        for (int ky = 0; ky < 3; ++ky) {
            const int y = h + ky - 1;
            if (y < 0 || y > 63) continue;
            const u16* row = plane + (y << 6);
#pragma unroll
            for (int kx = 0; kx < 3; ++kx) {
                const int x = w + kx - 1;
                const float xv = (x >= 0 && x <= 63) ? bf2f(row[x]) : 0.f;
                acc += xv * wk[ky * 3 + kx];
            }
        }
    }
    offs[(((size_t)(b * 18 + o)) << 12) + (h << 6) + w] = acc;
}

// ---------------------------------------------------------------------------
// Deformable im2col sampling: ST[n=8192][ck=2304] bf16.
// Block = (h, b, cq of 8); covers 32 c (288 ck rows) x 64 w.
// ---------------------------------------------------------------------------
__global__ __launch_bounds__(256) void sample_k(
    const u16* __restrict__ out1,   // [256][8192]
    const float* __restrict__ offs, // [2][18][4096]
    u16* __restrict__ ST)           // [8192][2304]
{
    __shared__ int4   s_ofs[576];
    __shared__ float4 s_w[576];
    __shared__ u16    s_tile[64][288];

    const int h  = blockIdx.x;
    const int b  = blockIdx.y;
    const int cq = blockIdx.z;
    const int c0 = cq << 5;
    const int tid = threadIdx.x;

    for (int p = tid; p < 576; p += 256) {
        const int k = p >> 6;
        const int w = p & 63;
        const float dy = offs[(((size_t)(b * 18 + 2 * k)) << 12) + (h << 6) + w];
        const float dx = offs[(((size_t)(b * 18 + 2 * k + 1)) << 12) + (h << 6) + w];
        const float py = (float)h + (float)(k / 3 - 1) + dy;
        const float px = (float)w + (float)(k % 3 - 1) + dx;
        const float y0f = floorf(py), x0f = floorf(px);
        const int y0 = (int)y0f, x0 = (int)x0f;
        const float wy1 = py - y0f, wx1 = px - x0f;
        const float wy0 = 1.f - wy1, wx0 = 1.f - wx1;
        const int y1 = y0 + 1, x1 = x0 + 1;
        const bool vy0 = (y0 >= 0) && (y0 < 64);
        const bool vy1 = (y1 >= 0) && (y1 < 64);
        const bool vx0 = (x0 >= 0) && (x0 < 64);
        const bool vx1 = (x1 >= 0) && (x1 < 64);
        const int cy0 = min(max(y0, 0), 63), cy1 = min(max(y1, 0), 63);
        const int cx0 = min(max(x0, 0), 63), cx1 = min(max(x1, 0), 63);
        int4 o4; float4 w4;
        o4.x = (cy0 << 6) + cx0;  w4.x = wy0 * wx0 * ((vy0 && vx0) ? 1.f : 0.f);
        o4.y = (cy0 << 6) + cx1;  w4.y = wy0 * wx1 * ((vy0 && vx1) ? 1.f : 0.f);
        o4.z = (cy1 << 6) + cx0;  w4.z = wy1 * wx0 * ((vy1 && vx0) ? 1.f : 0.f);
        o4.w = (cy1 << 6) + cx1;  w4.w = wy1 * wx1 * ((vy1 && vx1) ? 1.f : 0.f);
        s_ofs[p] = o4; s_w[p] = w4;
    }
    __syncthreads();

    const int w  = tid & 63;
    const int rg = tid >> 6;   // 0..3
    for (int cc = rg; cc < 32; cc += 4) {
        const u16* plane = out1 + (size_t)(c0 + cc) * 8192 + b * 4096;
#pragma unroll
        for (int k = 0; k < 9; ++k) {
            const int p = (k << 6) + w;
            const int4   o4 = s_ofs[p];
            const float4 w4 = s_w[p];
            const float val = w4.x * bf2f(plane[o4.x]) + w4.y * bf2f(plane[o4.y])
                            + w4.z * bf2f(plane[o4.z]) + w4.w * bf2f(plane[o4.w]);
            s_tile[w][cc * 9 + k] = f2bf(val);
        }
    }
    __syncthreads();

    const int row = tid >> 2, seg = tid & 3;
    u16* dst = ST + (size_t)(b * 4096 + h * 64 + row) * 2304 + cq * 288 + seg * 72;
    const u16* src = &s_tile[row][seg * 72];
#pragma unroll
    for (int q = 0; q < 9; q++)
        *(uint4*)(dst + q * 8) = *(const uint4*)(src + q * 8);
}

// ---------------------------------------------------------------------------
extern "C" void kernel_launch(void* const* d_in, const int* in_sizes, int n_in,
                              void* d_out, int out_size, void* d_ws, size_t ws_size,
                              hipStream_t stream) {
    const float* x     = (const float*)d_in[0];
    const float* w1    = (const float*)d_in[1];
    const float* g1    = (const float*)d_in[2];
    const float* b1    = (const float*)d_in[3];
    const float* m1    = (const float*)d_in[4];
    const float* v1    = (const float*)d_in[5];
    const float* w_off = (const float*)d_in[6];
    const float* b_off = (const float*)d_in[7];
    const float* w2    = (const float*)d_in[8];
    const float* g2    = (const float*)d_in[9];
    const float* b2    = (const float*)d_in[10];
    const float* m2    = (const float*)d_in[11];
    const float* v2    = (const float*)d_in[12];
    const float* w3    = (const float*)d_in[13];
    const float* g3    = (const float*)d_in[14];
    const float* b3    = (const float*)d_in[15];
    const float* m3    = (const float*)d_in[16];
    const float* v3    = (const float*)d_in[17];
    float* out = (float*)d_out;

    char* ws = (char*)d_ws;
    u16*  xbT  = (u16*)ws;              ws += (size_t)8192 * 1024 * 2;  // 16.78 MB
    u16*  wb1  = (u16*)ws;              ws += (size_t)256 * 1024 * 2;
    u16*  wb2  = (u16*)ws;              ws += (size_t)256 * 2304 * 2;
    u16*  wb3  = (u16*)ws;              ws += (size_t)1024 * 256 * 2;
    u16*  out1 = (u16*)ws;              ws += (size_t)256 * 8192 * 2;   // 4.19 MB
    float* offs = (float*)ws;           ws += (size_t)2 * 18 * 4096 * 4;
    u16*  ST   = (u16*)ws;              ws += (size_t)8192 * 2304 * 2;  // 37.75 MB
    u16*  o2T  = (u16*)ws;              ws += (size_t)8192 * 256 * 2;   // 4.19 MB

    // weight conversions
    cvt_w<<<dim3((262144 / 4 + 255) / 256), 256, 0, stream>>>(w1, wb1, 262144 / 4);
    cvt_w<<<dim3((589824 / 4 + 255) / 256), 256, 0, stream>>>(w2, wb2, 589824 / 4);
    cvt_w<<<dim3((262144 / 4 + 255) / 256), 256, 0, stream>>>(w3, wb3, 262144 / 4);
    // x -> xbT (transpose + cvt)
    cvt_x_T<<<dim3(64, 16, 2), 256, 0, stream>>>(x, xbT);

    // Stage 1: out1[c][n] bf16
    gemm_bn<0><<<dim3(64, 4), 256, 12288, stream>>>(
        wb1, xbT, g1, b1, m1, v1, nullptr, out1, 1024);

    // Stage 2: offsets
    offset_conv<<<dim3(64, 18, 2), 64, 0, stream>>>(out1, w_off, b_off, offs);

    // Stage 3a: deformable im2col ST[n][ck]
    sample_k<<<dim3(64, 2, 8), 256, 0, stream>>>(out1, offs, ST);

    // Stage 3b: deform GEMM -> out2T[n][o] bf16 (BN2+ReLU fused)
    gemm_bn<1><<<dim3(64, 4), 256, 12288 + 128 * 72 * 2, stream>>>(
        wb2, ST, g2, b2, m2, v2, nullptr, o2T, 2304);

    // Stage 4: conv1x1 + BN3 + resid + ReLU -> fp32 out
    gemm_bn<2><<<dim3(64, 16), 256, 12288, stream>>>(
        wb3, o2T, g3, b3, m3, v3, x, out, 256);
}

// Round 3
// 191.435 us; speedup vs baseline: 3.5443x; 2.5812x over previous
//
#include <hip/hip_runtime.h>
#include <hip/hip_bf16.h>

#define EPSV 1e-5f

typedef __attribute__((ext_vector_type(4))) float f32x4;
typedef __attribute__((ext_vector_type(8))) short bf16x8;
typedef unsigned short u16;
typedef unsigned int u32;

#define AS1(p) ((const __attribute__((address_space(1))) void*)(p))
#define AS3(p) ((__attribute__((address_space(3))) void*)(p))

__device__ __forceinline__ float bf2f(u16 u) {
    union { u32 i; float f; } x; x.i = ((u32)u) << 16; return x.f;
}
__device__ __forceinline__ u16 f2bf(float f) {
    __hip_bfloat16 h = __float2bfloat16(f);
    return *reinterpret_cast<u16*>(&h);
}

// ---------------------------------------------------------------------------
// fp32 -> bf16 elementwise (plain weights). n4 = n/4.
// ---------------------------------------------------------------------------
__global__ __launch_bounds__(256) void cvt_w(const float* __restrict__ in,
                                             u16* __restrict__ out, int n4) {
    int i = blockIdx.x * 256 + threadIdx.x;
    if (i < n4) {
        float4 v = ((const float4*)in)[i];
        ushort4 o;
        o.x = f2bf(v.x); o.y = f2bf(v.y); o.z = f2bf(v.z); o.w = f2bf(v.w);
        ((ushort4*)out)[i] = o;
    }
}

// ---------------------------------------------------------------------------
// 3x3-conv weight reorg: src fp32 [O][256][9] -> dst bf16 [gridDim.x][k*256+c]
// rows o >= O zero-padded.
// ---------------------------------------------------------------------------
__global__ __launch_bounds__(256) void reorg_w(const float* __restrict__ src,
                                               u16* __restrict__ dst, int O) {
    const int o = blockIdx.x;
    const int c = threadIdx.x;
#pragma unroll
    for (int k = 0; k < 9; k++) {
        float v = (o < O) ? src[((size_t)(o * 256 + c)) * 9 + k] : 0.f;
        dst[(size_t)o * 2304 + k * 256 + c] = f2bf(v);
    }
}

__global__ __launch_bounds__(256) void zfill(u16* __restrict__ p, int n) {
    int i = blockIdx.x * 256 + threadIdx.x;
    if (i < n) p[i] = 0;
}

// ---------------------------------------------------------------------------
// x [2][1024][4096] fp32  ->  xbT [8192][1024] bf16   (n = b*4096+hw)
// ---------------------------------------------------------------------------
__global__ __launch_bounds__(256) void cvt_x_T(const float* __restrict__ x,
                                               u16* __restrict__ xbT) {
    __shared__ u16 tile[64][72];
    const int tid = threadIdx.x;
    const int hw0 = blockIdx.x << 6;
    const int c0  = blockIdx.y << 6;
    const int b   = blockIdx.z;
    const int cl  = tid >> 4;
    const int hwl = (tid & 15) << 2;
#pragma unroll
    for (int i = 0; i < 4; i++) {
        const int c = cl + i * 16;
        float4 v = *(const float4*)(x + (((size_t)(b * 1024 + c0 + c)) << 12) + hw0 + hwl);
        tile[hwl + 0][c] = f2bf(v.x);
        tile[hwl + 1][c] = f2bf(v.y);
        tile[hwl + 2][c] = f2bf(v.z);
        tile[hwl + 3][c] = f2bf(v.w);
    }
    __syncthreads();
    const int hw  = tid >> 2;
    const int seg = tid & 3;
    u16* dst = xbT + ((size_t)(b * 4096 + hw0 + hw)) * 1024 + c0 + seg * 16;
    const u16* src = &tile[hw][seg * 16];
#pragma unroll
    for (int q = 0; q < 2; q++)
        *(uint4*)(dst + q * 8) = *(const uint4*)(src + q * 8);
}

// ---------------------------------------------------------------------------
// Templated MFMA GEMM (64x128 tile, BK=32, 4 waves 2x2).
// MODE 1: BN+ReLU -> bf16 outT[8192][M] (stride 256)
// MODE 2: BN + resid + ReLU -> fp32 out [2][M][4096]
// ---------------------------------------------------------------------------
template<int MODE>
__global__ __launch_bounds__(256) void gemm_bn(
    const u16* __restrict__ A, const u16* __restrict__ BT,
    const float* __restrict__ g, const float* __restrict__ bb,
    const float* __restrict__ m, const float* __restrict__ v,
    const float* __restrict__ resid, void* __restrict__ out, int K)
{
    extern __shared__ char sm[];
    u16* As = (u16*)sm;            // [64][32]
    u16* Bs = (u16*)(sm + 4096);   // [128][32]

    const int tid  = threadIdx.x;
    const int lane = tid & 63;
    const int wid  = tid >> 6;
    const int n0 = blockIdx.x << 7;
    const int m0 = blockIdx.y << 6;
    const int wr = wid >> 1, wc = wid & 1;
    const int lr = lane & 15, kg = lane >> 4;

    f32x4 acc[2][4] = {};

    const int arow = tid >> 2, aseg = (tid & 3) << 3;
    const u16* aG  = A  + (size_t)(m0 + arow) * K + aseg;
    const u16* bG0 = BT + (size_t)(n0 + arow) * K + aseg;
    const u16* bG1 = BT + (size_t)(n0 + 64 + arow) * K + aseg;
    char* ldsA  = ((char*)As) + wid * 1024;
    char* ldsB0 = ((char*)Bs) + wid * 1024;
    char* ldsB1 = ((char*)Bs) + 4096 + wid * 1024;

    const u16* Asp = As + (wr * 32 + lr) * 32 + kg * 8;
    const u16* Bsp = Bs + (wc * 64 + lr) * 32 + kg * 8;

    for (int kt = 0; kt < K; kt += 32) {
        __builtin_amdgcn_global_load_lds(AS1(aG  + kt), AS3(ldsA),  16, 0, 0);
        __builtin_amdgcn_global_load_lds(AS1(bG0 + kt), AS3(ldsB0), 16, 0, 0);
        __builtin_amdgcn_global_load_lds(AS1(bG1 + kt), AS3(ldsB1), 16, 0, 0);
        __syncthreads();
        bf16x8 a0 = *(const bf16x8*)(Asp);
        bf16x8 a1 = *(const bf16x8*)(Asp + 512);
        bf16x8 b0 = *(const bf16x8*)(Bsp);
        bf16x8 b1 = *(const bf16x8*)(Bsp + 512);
        bf16x8 b2 = *(const bf16x8*)(Bsp + 1024);
        bf16x8 b3 = *(const bf16x8*)(Bsp + 1536);
        acc[0][0] = __builtin_amdgcn_mfma_f32_16x16x32_bf16(a0, b0, acc[0][0], 0, 0, 0);
        acc[0][1] = __builtin_amdgcn_mfma_f32_16x16x32_bf16(a0, b1, acc[0][1], 0, 0, 0);
        acc[0][2] = __builtin_amdgcn_mfma_f32_16x16x32_bf16(a0, b2, acc[0][2], 0, 0, 0);
        acc[0][3] = __builtin_amdgcn_mfma_f32_16x16x32_bf16(a0, b3, acc[0][3], 0, 0, 0);
        acc[1][0] = __builtin_amdgcn_mfma_f32_16x16x32_bf16(a1, b0, acc[1][0], 0, 0, 0);
        acc[1][1] = __builtin_amdgcn_mfma_f32_16x16x32_bf16(a1, b1, acc[1][1], 0, 0, 0);
        acc[1][2] = __builtin_amdgcn_mfma_f32_16x16x32_bf16(a1, b2, acc[1][2], 0, 0, 0);
        acc[1][3] = __builtin_amdgcn_mfma_f32_16x16x32_bf16(a1, b3, acc[1][3], 0, 0, 0);
        __syncthreads();
    }

    float sc[2][4], tc[2][4];
#pragma unroll
    for (int mm = 0; mm < 2; mm++)
#pragma unroll
        for (int r = 0; r < 4; r++) {
            const int o = m0 + wr * 32 + mm * 16 + kg * 4 + r;
            const float s = g[o] * rsqrtf(v[o] + EPSV);
            sc[mm][r] = s;
            tc[mm][r] = bb[o] - m[o] * s;
        }

    if (MODE == 1) {
        u16* T = (u16*)(sm + 12288);   // [128][72]
#pragma unroll
        for (int mm = 0; mm < 2; mm++) {
            const int ol = wr * 32 + mm * 16 + kg * 4;
#pragma unroll
            for (int j = 0; j < 4; j++) {
                const int nl = wc * 64 + j * 16 + lr;
                float v0 = acc[mm][j][0] * sc[mm][0] + tc[mm][0];
                float v1 = acc[mm][j][1] * sc[mm][1] + tc[mm][1];
                float v2 = acc[mm][j][2] * sc[mm][2] + tc[mm][2];
                float v3 = acc[mm][j][3] * sc[mm][3] + tc[mm][3];
                v0 = v0 > 0.f ? v0 : 0.f; v1 = v1 > 0.f ? v1 : 0.f;
                v2 = v2 > 0.f ? v2 : 0.f; v3 = v3 > 0.f ? v3 : 0.f;
                u32 p01 = (u32)f2bf(v0) | ((u32)f2bf(v1) << 16);
                u32 p23 = (u32)f2bf(v2) | ((u32)f2bf(v3) << 16);
                *(u32*)&T[nl * 72 + ol]     = p01;
                *(u32*)&T[nl * 72 + ol + 2] = p23;
            }
        }
        __syncthreads();
        const int nl = tid >> 1, half = tid & 1;
        u16* dst = (u16*)out + (size_t)(n0 + nl) * 256 + m0 + half * 32;
        const u16* src = &T[nl * 72 + half * 32];
#pragma unroll
        for (int q = 0; q < 4; q++)
            *(uint4*)(dst + q * 8) = *(const uint4*)(src + q * 8);
    } else {
        float* O = (float*)out;
#pragma unroll
        for (int mm = 0; mm < 2; mm++)
#pragma unroll
            for (int r = 0; r < 4; r++) {
                const int o = m0 + wr * 32 + mm * 16 + kg * 4 + r;
#pragma unroll
                for (int j = 0; j < 4; j++) {
                    const int n = n0 + wc * 64 + j * 16 + lr;
                    const size_t idx = ((size_t)(n >> 12) << 22) + ((size_t)o << 12) + (n & 4095);
                    float val = acc[mm][j][r] * sc[mm][r] + tc[mm][r] + resid[idx];
                    O[idx] = val > 0.f ? val : 0.f;
                }
            }
    }
}

// ---------------------------------------------------------------------------
// Offset conv as MFMA GEMM with implicit im2col.
// offs[o][n] = b_off[o] + sum_{k,c} Woff[o][k*256+c] * out1T[n+shift_k][c]
// B staged from out1T with per-row tap shift; invalid rows -> zbuf.
// ---------------------------------------------------------------------------
__global__ __launch_bounds__(256) void gemm_off(
    const u16* __restrict__ A,      // [64][2304] (rows >=18 zero)
    const u16* __restrict__ out1T,  // [8192][256]
    const u16* __restrict__ zbuf,   // >=64B zeros
    const float* __restrict__ b_off,
    float* __restrict__ offs)       // [2][18][4096]
{
    __shared__ char sm[12288];
    u16* As = (u16*)sm;
    u16* Bs = (u16*)(sm + 4096);

    const int tid  = threadIdx.x;
    const int lane = tid & 63;
    const int wid  = tid >> 6;
    const int n0 = blockIdx.x << 7;
    const int wr = wid >> 1, wc = wid & 1;
    const int lr = lane & 15, kg = lane >> 4;

    f32x4 acc[2][4] = {};

    const int arow = tid >> 2, aseg = (tid & 3) << 3;
    const u16* aG = A + (size_t)arow * 2304 + aseg;
    const int nB0 = n0 + arow, nB1 = n0 + 64 + arow;
    const int y0r = (nB0 & 4095) >> 6, x0r = nB0 & 63;
    const int y1r = (nB1 & 4095) >> 6, x1r = nB1 & 63;

    char* ldsA  = sm + wid * 1024;
    char* ldsB0 = sm + 4096 + wid * 1024;
    char* ldsB1 = sm + 8192 + wid * 1024;

    const u16* Asp = As + (wr * 32 + lr) * 32 + kg * 8;
    const u16* Bsp = Bs + (wc * 64 + lr) * 32 + kg * 8;

    for (int kt = 0; kt < 2304; kt += 32) {
        const int tap = kt >> 8, c0 = kt & 255;
        const int dy = tap / 3 - 1, dx = tap % 3 - 1;
        const int sh = dy * 64 + dx;
        const bool v0 = ((unsigned)(y0r + dy) < 64u) && ((unsigned)(x0r + dx) < 64u);
        const bool v1 = ((unsigned)(y1r + dy) < 64u) && ((unsigned)(x1r + dx) < 64u);
        const u16* s0 = v0 ? out1T + (size_t)(nB0 + sh) * 256 + c0 + aseg : zbuf + aseg;
        const u16* s1 = v1 ? out1T + (size_t)(nB1 + sh) * 256 + c0 + aseg : zbuf + aseg;
        __builtin_amdgcn_global_load_lds(AS1(aG + kt), AS3(ldsA),  16, 0, 0);
        __builtin_amdgcn_global_load_lds(AS1(s0),      AS3(ldsB0), 16, 0, 0);
        __builtin_amdgcn_global_load_lds(AS1(s1),      AS3(ldsB1), 16, 0, 0);
        __syncthreads();
        bf16x8 a0 = *(const bf16x8*)(Asp);
        bf16x8 a1 = *(const bf16x8*)(Asp + 512);
        bf16x8 b0 = *(const bf16x8*)(Bsp);
        bf16x8 b1 = *(const bf16x8*)(Bsp + 512);
        bf16x8 b2 = *(const bf16x8*)(Bsp + 1024);
        bf16x8 b3 = *(const bf16x8*)(Bsp + 1536);
        acc[0][0] = __builtin_amdgcn_mfma_f32_16x16x32_bf16(a0, b0, acc[0][0], 0, 0, 0);
        acc[0][1] = __builtin_amdgcn_mfma_f32_16x16x32_bf16(a0, b1, acc[0][1], 0, 0, 0);
        acc[0][2] = __builtin_amdgcn_mfma_f32_16x16x32_bf16(a0, b2, acc[0][2], 0, 0, 0);
        acc[0][3] = __builtin_amdgcn_mfma_f32_16x16x32_bf16(a0, b3, acc[0][3], 0, 0, 0);
        acc[1][0] = __builtin_amdgcn_mfma_f32_16x16x32_bf16(a1, b0, acc[1][0], 0, 0, 0);
        acc[1][1] = __builtin_amdgcn_mfma_f32_16x16x32_bf16(a1, b1, acc[1][1], 0, 0, 0);
        acc[1][2] = __builtin_amdgcn_mfma_f32_16x16x32_bf16(a1, b2, acc[1][2], 0, 0, 0);
        acc[1][3] = __builtin_amdgcn_mfma_f32_16x16x32_bf16(a1, b3, acc[1][3], 0, 0, 0);
        __syncthreads();
    }

#pragma unroll
    for (int mm = 0; mm < 2; mm++)
#pragma unroll
        for (int r = 0; r < 4; r++) {
            const int o = wr * 32 + mm * 16 + kg * 4 + r;
            if (o < 18) {
                const float bo = b_off[o];
#pragma unroll
                for (int j = 0; j < 4; j++) {
                    const int n = n0 + wc * 64 + j * 16 + lr;
                    offs[(((size_t)((n >> 12) * 18 + o)) << 12) + (n & 4095)] =
                        acc[mm][j][r] + bo;
                }
            }
        }
}

// ---------------------------------------------------------------------------
// Deformable im2col: ST[n][k*256+c] bf16 from out1T [n][c].
// Block = (h, b, c-quarter). Vectorized corner-row loads.
// ---------------------------------------------------------------------------
__global__ __launch_bounds__(256) void sample_k(
    const u16* __restrict__ out1T,  // [8192][256]
    const float* __restrict__ offs, // [2][18][4096]
    u16* __restrict__ ST)           // [8192][2304]
{
    __shared__ int4   s_ofs[576];
    __shared__ float4 s_w[576];

    const int h  = blockIdx.x;
    const int b  = blockIdx.y;
    const int cs = blockIdx.z << 6;   // c-quarter base
    const int tid = threadIdx.x;

    for (int p = tid; p < 576; p += 256) {
        const int k = p >> 6;
        const int w = p & 63;
        const float dy = offs[(((size_t)(b * 18 + 2 * k)) << 12) + (h << 6) + w];
        const float dx = offs[(((size_t)(b * 18 + 2 * k + 1)) << 12) + (h << 6) + w];
        const float py = (float)h + (float)(k / 3 - 1) + dy;
        const float px = (float)w + (float)(k % 3 - 1) + dx;
        const float y0f = floorf(py), x0f = floorf(px);
        const int y0 = (int)y0f, x0 = (int)x0f;
        const float wy1 = py - y0f, wx1 = px - x0f;
        const float wy0 = 1.f - wy1, wx0 = 1.f - wx1;
        const int y1 = y0 + 1, x1 = x0 + 1;
        const bool vy0 = (y0 >= 0) && (y0 < 64);
        const bool vy1 = (y1 >= 0) && (y1 < 64);
        const bool vx0 = (x0 >= 0) && (x0 < 64);
        const bool vx1 = (x1 >= 0) && (x1 < 64);
        const int cy0 = min(max(y0, 0), 63), cy1 = min(max(y1, 0), 63);
        const int cx0 = min(max(x0, 0), 63), cx1 = min(max(x1, 0), 63);
        int4 o4; float4 w4;
        o4.x = (cy0 << 6) + cx0;  w4.x = wy0 * wx0 * ((vy0 && vx0) ? 1.f : 0.f);
        o4.y = (cy0 << 6) + cx1;  w4.y = wy0 * wx1 * ((vy0 && vx1) ? 1.f : 0.f);
        o4.z = (cy1 << 6) + cx0;  w4.z = wy1 * wx0 * ((vy1 && vx0) ? 1.f : 0.f);
        o4.w = (cy1 << 6) + cx1;  w4.w = wy1 * wx1 * ((vy1 && vx1) ? 1.f : 0.f);
        s_ofs[p] = o4; s_w[p] = w4;
    }
    __syncthreads();

    const u16* base = out1T + (((size_t)b) << 12) * 256;
    for (int p = tid; p < 576; p += 256) {
        const int k = p >> 6;
        const int w = p & 63;
        const int4   o4 = s_ofs[p];
        const float4 w4 = s_w[p];
        const u16* r0 = base + (size_t)o4.x * 256 + cs;
        const u16* r1 = base + (size_t)o4.y * 256 + cs;
        const u16* r2 = base + (size_t)o4.z * 256 + cs;
        const u16* r3 = base + (size_t)o4.w * 256 + cs;
        u16* dst = ST + ((size_t)(b * 4096 + h * 64 + w)) * 2304 + k * 256 + cs;
#pragma unroll
        for (int c0 = 0; c0 < 64; c0 += 8) {
            bf16x8 v0 = *(const bf16x8*)(r0 + c0);
            bf16x8 v1 = *(const bf16x8*)(r1 + c0);
            bf16x8 v2 = *(const bf16x8*)(r2 + c0);
            bf16x8 v3 = *(const bf16x8*)(r3 + c0);
            bf16x8 ov;
#pragma unroll
            for (int i = 0; i < 8; i++) {
                const float f = w4.x * bf2f((u16)v0[i]) + w4.y * bf2f((u16)v1[i])
                              + w4.z * bf2f((u16)v2[i]) + w4.w * bf2f((u16)v3[i]);
                ov[i] = (short)f2bf(f);
            }
            *(bf16x8*)(dst + c0) = ov;
        }
    }
}

// ---------------------------------------------------------------------------
extern "C" void kernel_launch(void* const* d_in, const int* in_sizes, int n_in,
                              void* d_out, int out_size, void* d_ws, size_t ws_size,
                              hipStream_t stream) {
    const float* x     = (const float*)d_in[0];
    const float* w1    = (const float*)d_in[1];
    const float* g1    = (const float*)d_in[2];
    const float* b1    = (const float*)d_in[3];
    const float* m1    = (const float*)d_in[4];
    const float* v1    = (const float*)d_in[5];
    const float* w_off = (const float*)d_in[6];
    const float* b_off = (const float*)d_in[7];
    const float* w2    = (const float*)d_in[8];
    const float* g2    = (const float*)d_in[9];
    const float* b2    = (const float*)d_in[10];
    const float* m2    = (const float*)d_in[11];
    const float* v2    = (const float*)d_in[12];
    const float* w3    = (const float*)d_in[13];
    const float* g3    = (const float*)d_in[14];
    const float* b3    = (const float*)d_in[15];
    const float* m3    = (const float*)d_in[16];
    const float* v3    = (const float*)d_in[17];
    float* out = (float*)d_out;

    char* ws = (char*)d_ws;
    u16*  xbT   = (u16*)ws;   ws += (size_t)8192 * 1024 * 2;
    u16*  wb1   = (u16*)ws;   ws += (size_t)256 * 1024 * 2;
    u16*  wb3   = (u16*)ws;   ws += (size_t)1024 * 256 * 2;
    u16*  wOffP = (u16*)ws;   ws += (size_t)64 * 2304 * 2;
    u16*  wb2p  = (u16*)ws;   ws += (size_t)256 * 2304 * 2;
    u16*  zbuf  = (u16*)ws;   ws += (size_t)512 * 2;
    u16*  out1T = (u16*)ws;   ws += (size_t)8192 * 256 * 2;
    float* offs = (float*)ws; ws += (size_t)2 * 18 * 4096 * 4;
    u16*  ST    = (u16*)ws;   ws += (size_t)8192 * 2304 * 2;
    u16*  o2T   = (u16*)ws;   ws += (size_t)8192 * 256 * 2;

    // conversions / reorgs
    cvt_w<<<dim3(256), 256, 0, stream>>>(w1, wb1, 262144 / 4);
    cvt_w<<<dim3(256), 256, 0, stream>>>(w3, wb3, 262144 / 4);
    reorg_w<<<dim3(64), 256, 0, stream>>>(w_off, wOffP, 18);
    reorg_w<<<dim3(256), 256, 0, stream>>>(w2, wb2p, 256);
    zfill<<<dim3(2), 256, 0, stream>>>(zbuf, 512);
    cvt_x_T<<<dim3(64, 16, 2), 256, 0, stream>>>(x, xbT);

    // Stage 1: conv1x1 + BN1 + ReLU -> out1T [n][256]
    gemm_bn<1><<<dim3(64, 4), 256, 12288 + 128 * 72 * 2, stream>>>(
        wb1, xbT, g1, b1, m1, v1, nullptr, out1T, 1024);

    // Stage 2: offset conv via implicit-im2col MFMA GEMM
    gemm_off<<<dim3(64), 256, 0, stream>>>(wOffP, out1T, zbuf, b_off, offs);

    // Stage 3a: deformable im2col ST[n][k*256+c]
    sample_k<<<dim3(64, 2, 4), 256, 0, stream>>>(out1T, offs, ST);

    // Stage 3b: deform GEMM + BN2 + ReLU -> o2T [n][256]
    gemm_bn<1><<<dim3(64, 4), 256, 12288 + 128 * 72 * 2, stream>>>(
        wb2p, ST, g2, b2, m2, v2, nullptr, o2T, 2304);

    // Stage 4: conv1x1 + BN3 + resid + ReLU -> fp32 out
    gemm_bn<2><<<dim3(64, 16), 256, 12288, stream>>>(
        wb3, o2T, g3, b3, m3, v3, x, out, 256);
}

// Round 4
// 153.067 us; speedup vs baseline: 4.4327x; 1.2507x over previous
//
#include <hip/hip_runtime.h>
#include <hip/hip_bf16.h>

#define EPSV 1e-5f

typedef __attribute__((ext_vector_type(4))) float f32x4;
typedef __attribute__((ext_vector_type(8))) short bf16x8;
typedef unsigned short u16;
typedef unsigned int u32;

#define AS1(p) ((const __attribute__((address_space(1))) void*)(p))
#define AS3(p) ((__attribute__((address_space(3))) void*)(p))

__device__ __forceinline__ float bf2f(u16 u) {
    union { u32 i; float f; } x; x.i = ((u32)u) << 16; return x.f;
}
__device__ __forceinline__ u16 f2bf(float f) {
    __hip_bfloat16 h = __float2bfloat16(f);
    return *reinterpret_cast<u16*>(&h);
}

// ---------------------------------------------------------------------------
// fp32 -> bf16 elementwise (plain weights). n4 = n/4.
// ---------------------------------------------------------------------------
__global__ __launch_bounds__(256) void cvt_w(const float* __restrict__ in,
                                             u16* __restrict__ out, int n4) {
    int i = blockIdx.x * 256 + threadIdx.x;
    if (i < n4) {
        float4 v = ((const float4*)in)[i];
        ushort4 o;
        o.x = f2bf(v.x); o.y = f2bf(v.y); o.z = f2bf(v.z); o.w = f2bf(v.w);
        ((ushort4*)out)[i] = o;
    }
}

// ---------------------------------------------------------------------------
// 3x3-conv weight reorg: src fp32 [O][256][9] -> dst bf16 [gridDim.x][k*256+c]
// ---------------------------------------------------------------------------
__global__ __launch_bounds__(256) void reorg_w(const float* __restrict__ src,
                                               u16* __restrict__ dst, int O) {
    const int o = blockIdx.x;
    const int c = threadIdx.x;
#pragma unroll
    for (int k = 0; k < 9; k++) {
        float v = (o < O) ? src[((size_t)(o * 256 + c)) * 9 + k] : 0.f;
        dst[(size_t)o * 2304 + k * 256 + c] = f2bf(v);
    }
}

__global__ __launch_bounds__(256) void zfill(u16* __restrict__ p, int n) {
    int i = blockIdx.x * 256 + threadIdx.x;
    if (i < n) p[i] = 0;
}

// ---------------------------------------------------------------------------
// x [2][1024][4096] fp32  ->  xbT [8192][1024] bf16   (n = b*4096+hw)
// ---------------------------------------------------------------------------
__global__ __launch_bounds__(256) void cvt_x_T(const float* __restrict__ x,
                                               u16* __restrict__ xbT) {
    __shared__ u16 tile[64][72];
    const int tid = threadIdx.x;
    const int hw0 = blockIdx.x << 6;
    const int c0  = blockIdx.y << 6;
    const int b   = blockIdx.z;
    const int cl  = tid >> 4;
    const int hwl = (tid & 15) << 2;
#pragma unroll
    for (int i = 0; i < 4; i++) {
        const int c = cl + i * 16;
        float4 v = *(const float4*)(x + (((size_t)(b * 1024 + c0 + c)) << 12) + hw0 + hwl);
        tile[hwl + 0][c] = f2bf(v.x);
        tile[hwl + 1][c] = f2bf(v.y);
        tile[hwl + 2][c] = f2bf(v.z);
        tile[hwl + 3][c] = f2bf(v.w);
    }
    __syncthreads();
    const int hw  = tid >> 2;
    const int seg = tid & 3;
    u16* dst = xbT + ((size_t)(b * 4096 + hw0 + hw)) * 1024 + c0 + seg * 16;
    const u16* src = &tile[hw][seg * 16];
#pragma unroll
    for (int q = 0; q < 2; q++)
        *(uint4*)(dst + q * 8) = *(const uint4*)(src + q * 8);
}

// ---------------------------------------------------------------------------
// Templated MFMA GEMM (64x128 tile, BK=32, 4 waves 2x2).
// MODE 1: BN+ReLU -> bf16 outT[8192][M] (stride 256)
// MODE 2: BN + resid + ReLU -> fp32 out [2][M][4096], LDS-transposed epilogue
// ---------------------------------------------------------------------------
template<int MODE>
__global__ __launch_bounds__(256) void gemm_bn(
    const u16* __restrict__ A, const u16* __restrict__ BT,
    const float* __restrict__ g, const float* __restrict__ bb,
    const float* __restrict__ m, const float* __restrict__ v,
    const float* __restrict__ resid, void* __restrict__ out, int K)
{
    extern __shared__ char sm[];
    u16* As = (u16*)sm;            // [64][32]
    u16* Bs = (u16*)(sm + 4096);   // [128][32]

    const int tid  = threadIdx.x;
    const int lane = tid & 63;
    const int wid  = tid >> 6;
    const int n0 = blockIdx.x << 7;
    const int m0 = blockIdx.y << 6;
    const int wr = wid >> 1, wc = wid & 1;
    const int lr = lane & 15, kg = lane >> 4;

    f32x4 acc[2][4] = {};

    const int arow = tid >> 2, aseg = (tid & 3) << 3;
    const u16* aG  = A  + (size_t)(m0 + arow) * K + aseg;
    const u16* bG0 = BT + (size_t)(n0 + arow) * K + aseg;
    const u16* bG1 = BT + (size_t)(n0 + 64 + arow) * K + aseg;
    char* ldsA  = ((char*)As) + wid * 1024;
    char* ldsB0 = ((char*)Bs) + wid * 1024;
    char* ldsB1 = ((char*)Bs) + 4096 + wid * 1024;

    const u16* Asp = As + (wr * 32 + lr) * 32 + kg * 8;
    const u16* Bsp = Bs + (wc * 64 + lr) * 32 + kg * 8;

    for (int kt = 0; kt < K; kt += 32) {
        __builtin_amdgcn_global_load_lds(AS1(aG  + kt), AS3(ldsA),  16, 0, 0);
        __builtin_amdgcn_global_load_lds(AS1(bG0 + kt), AS3(ldsB0), 16, 0, 0);
        __builtin_amdgcn_global_load_lds(AS1(bG1 + kt), AS3(ldsB1), 16, 0, 0);
        __syncthreads();
        bf16x8 a0 = *(const bf16x8*)(Asp);
        bf16x8 a1 = *(const bf16x8*)(Asp + 512);
        bf16x8 b0 = *(const bf16x8*)(Bsp);
        bf16x8 b1 = *(const bf16x8*)(Bsp + 512);
        bf16x8 b2 = *(const bf16x8*)(Bsp + 1024);
        bf16x8 b3 = *(const bf16x8*)(Bsp + 1536);
        acc[0][0] = __builtin_amdgcn_mfma_f32_16x16x32_bf16(a0, b0, acc[0][0], 0, 0, 0);
        acc[0][1] = __builtin_amdgcn_mfma_f32_16x16x32_bf16(a0, b1, acc[0][1], 0, 0, 0);
        acc[0][2] = __builtin_amdgcn_mfma_f32_16x16x32_bf16(a0, b2, acc[0][2], 0, 0, 0);
        acc[0][3] = __builtin_amdgcn_mfma_f32_16x16x32_bf16(a0, b3, acc[0][3], 0, 0, 0);
        acc[1][0] = __builtin_amdgcn_mfma_f32_16x16x32_bf16(a1, b0, acc[1][0], 0, 0, 0);
        acc[1][1] = __builtin_amdgcn_mfma_f32_16x16x32_bf16(a1, b1, acc[1][1], 0, 0, 0);
        acc[1][2] = __builtin_amdgcn_mfma_f32_16x16x32_bf16(a1, b2, acc[1][2], 0, 0, 0);
        acc[1][3] = __builtin_amdgcn_mfma_f32_16x16x32_bf16(a1, b3, acc[1][3], 0, 0, 0);
        __syncthreads();
    }

    float sc[2][4], tc[2][4];
#pragma unroll
    for (int mm = 0; mm < 2; mm++)
#pragma unroll
        for (int r = 0; r < 4; r++) {
            const int o = m0 + wr * 32 + mm * 16 + kg * 4 + r;
            const float s = g[o] * rsqrtf(v[o] + EPSV);
            sc[mm][r] = s;
            tc[mm][r] = bb[o] - m[o] * s;
        }

    if (MODE == 1) {
        u16* T = (u16*)(sm + 12288);   // [128][72]
#pragma unroll
        for (int mm = 0; mm < 2; mm++) {
            const int ol = wr * 32 + mm * 16 + kg * 4;
#pragma unroll
            for (int j = 0; j < 4; j++) {
                const int nl = wc * 64 + j * 16 + lr;
                float v0 = acc[mm][j][0] * sc[mm][0] + tc[mm][0];
                float v1 = acc[mm][j][1] * sc[mm][1] + tc[mm][1];
                float v2 = acc[mm][j][2] * sc[mm][2] + tc[mm][2];
                float v3 = acc[mm][j][3] * sc[mm][3] + tc[mm][3];
                v0 = v0 > 0.f ? v0 : 0.f; v1 = v1 > 0.f ? v1 : 0.f;
                v2 = v2 > 0.f ? v2 : 0.f; v3 = v3 > 0.f ? v3 : 0.f;
                u32 p01 = (u32)f2bf(v0) | ((u32)f2bf(v1) << 16);
                u32 p23 = (u32)f2bf(v2) | ((u32)f2bf(v3) << 16);
                *(u32*)&T[nl * 72 + ol]     = p01;
                *(u32*)&T[nl * 72 + ol + 2] = p23;
            }
        }
        __syncthreads();
        const int nl = tid >> 1, half = tid & 1;
        u16* dst = (u16*)out + (size_t)(n0 + nl) * 256 + m0 + half * 32;
        const u16* src = &T[nl * 72 + half * 32];
#pragma unroll
        for (int q = 0; q < 4; q++)
            *(uint4*)(dst + q * 8) = *(const uint4*)(src + q * 8);
    } else {
        // LDS transpose: [64 o][132 n] fp32
        float* T = (float*)(sm + 12288);
#pragma unroll
        for (int mm = 0; mm < 2; mm++) {
            const int ol = wr * 32 + mm * 16 + kg * 4;
#pragma unroll
            for (int j = 0; j < 4; j++) {
                const int nl = wc * 64 + j * 16 + lr;
#pragma unroll
                for (int r = 0; r < 4; r++)
                    T[(ol + r) * 132 + nl] = acc[mm][j][r] * sc[mm][r] + tc[mm][r];
            }
        }
        __syncthreads();
        float* O = (float*)out;
        for (int idx = tid; idx < 2048; idx += 256) {
            const int ol  = idx >> 5;
            const int nl4 = (idx & 31) << 2;
            const int n = n0 + nl4;
            const size_t gidx = ((size_t)(n >> 12) << 22) + ((size_t)(m0 + ol) << 12) + (n & 4095);
            float4 rv = *(const float4*)(resid + gidx);
            float4 ov;
            ov.x = T[ol * 132 + nl4 + 0] + rv.x;
            ov.y = T[ol * 132 + nl4 + 1] + rv.y;
            ov.z = T[ol * 132 + nl4 + 2] + rv.z;
            ov.w = T[ol * 132 + nl4 + 3] + rv.w;
            ov.x = ov.x > 0.f ? ov.x : 0.f;
            ov.y = ov.y > 0.f ? ov.y : 0.f;
            ov.z = ov.z > 0.f ? ov.z : 0.f;
            ov.w = ov.w > 0.f ? ov.w : 0.f;
            *(float4*)(O + gidx) = ov;
        }
    }
}

// ---------------------------------------------------------------------------
// Offset conv as split-K implicit-im2col MFMA GEMM.
// Grid (64 n-tiles, 4 k-splits). Writes fp32 partials offsP[kz][b][18][4096].
// ---------------------------------------------------------------------------
__global__ __launch_bounds__(256) void gemm_off(
    const u16* __restrict__ A,      // [64][2304] (rows >=18 zero)
    const u16* __restrict__ out1T,  // [8192][256]
    const u16* __restrict__ zbuf,
    float* __restrict__ offsP)      // [4][2][18][4096]
{
    __shared__ char sm[12288];
    u16* As = (u16*)sm;
    u16* Bs = (u16*)(sm + 4096);

    const int tid  = threadIdx.x;
    const int lane = tid & 63;
    const int wid  = tid >> 6;
    const int n0 = blockIdx.x << 7;
    const int kz = blockIdx.y;
    const int wr = wid >> 1, wc = wid & 1;
    const int lr = lane & 15, kg = lane >> 4;

    f32x4 acc[2][4] = {};

    const int arow = tid >> 2, aseg = (tid & 3) << 3;
    const u16* aG = A + (size_t)arow * 2304 + aseg;
    const int nB0 = n0 + arow, nB1 = n0 + 64 + arow;
    const int y0r = (nB0 & 4095) >> 6, x0r = nB0 & 63;
    const int y1r = (nB1 & 4095) >> 6, x1r = nB1 & 63;

    char* ldsA  = sm + wid * 1024;
    char* ldsB0 = sm + 4096 + wid * 1024;
    char* ldsB1 = sm + 8192 + wid * 1024;

    const u16* Asp = As + (wr * 32 + lr) * 32 + kg * 8;
    const u16* Bsp = Bs + (wc * 64 + lr) * 32 + kg * 8;

    const int ktEnd = kz * 576 + 576;
    for (int kt = kz * 576; kt < ktEnd; kt += 32) {
        const int tap = kt >> 8, c0 = kt & 255;
        const int dy = tap / 3 - 1, dx = tap % 3 - 1;
        const int sh = dy * 64 + dx;
        const bool v0 = ((unsigned)(y0r + dy) < 64u) && ((unsigned)(x0r + dx) < 64u);
        const bool v1 = ((unsigned)(y1r + dy) < 64u) && ((unsigned)(x1r + dx) < 64u);
        const u16* s0 = v0 ? out1T + (size_t)(nB0 + sh) * 256 + c0 + aseg : zbuf + aseg;
        const u16* s1 = v1 ? out1T + (size_t)(nB1 + sh) * 256 + c0 + aseg : zbuf + aseg;
        __builtin_amdgcn_global_load_lds(AS1(aG + kt), AS3(ldsA),  16, 0, 0);
        __builtin_amdgcn_global_load_lds(AS1(s0),      AS3(ldsB0), 16, 0, 0);
        __builtin_amdgcn_global_load_lds(AS1(s1),      AS3(ldsB1), 16, 0, 0);
        __syncthreads();
        bf16x8 a0 = *(const bf16x8*)(Asp);
        bf16x8 a1 = *(const bf16x8*)(Asp + 512);
        bf16x8 b0 = *(const bf16x8*)(Bsp);
        bf16x8 b1 = *(const bf16x8*)(Bsp + 512);
        bf16x8 b2 = *(const bf16x8*)(Bsp + 1024);
        bf16x8 b3 = *(const bf16x8*)(Bsp + 1536);
        acc[0][0] = __builtin_amdgcn_mfma_f32_16x16x32_bf16(a0, b0, acc[0][0], 0, 0, 0);
        acc[0][1] = __builtin_amdgcn_mfma_f32_16x16x32_bf16(a0, b1, acc[0][1], 0, 0, 0);
        acc[0][2] = __builtin_amdgcn_mfma_f32_16x16x32_bf16(a0, b2, acc[0][2], 0, 0, 0);
        acc[0][3] = __builtin_amdgcn_mfma_f32_16x16x32_bf16(a0, b3, acc[0][3], 0, 0, 0);
        acc[1][0] = __builtin_amdgcn_mfma_f32_16x16x32_bf16(a1, b0, acc[1][0], 0, 0, 0);
        acc[1][1] = __builtin_amdgcn_mfma_f32_16x16x32_bf16(a1, b1, acc[1][1], 0, 0, 0);
        acc[1][2] = __builtin_amdgcn_mfma_f32_16x16x32_bf16(a1, b2, acc[1][2], 0, 0, 0);
        acc[1][3] = __builtin_amdgcn_mfma_f32_16x16x32_bf16(a1, b3, acc[1][3], 0, 0, 0);
        __syncthreads();
    }

#pragma unroll
    for (int mm = 0; mm < 2; mm++)
#pragma unroll
        for (int r = 0; r < 4; r++) {
            const int o = wr * 32 + mm * 16 + kg * 4 + r;
            if (o < 18) {
#pragma unroll
                for (int j = 0; j < 4; j++) {
                    const int n = n0 + wc * 64 + j * 16 + lr;
                    offsP[(size_t)kz * 147456 +
                          (((size_t)((n >> 12) * 18 + o)) << 12) + (n & 4095)] =
                        acc[mm][j][r];
                }
            }
        }
}

// ---------------------------------------------------------------------------
// Deformable im2col: ST[n][k*256+c]. One wave per sample point; lanes cover
// 128 channels (u32 = 2 bf16). Fully coalesced reads (4x256B) and store (256B).
// Grid (64 h, 2 b, 2 c-half), 256 threads.
// ---------------------------------------------------------------------------
__global__ __launch_bounds__(256) void sample_k(
    const u16* __restrict__ out1T,  // [8192][256]
    const float* __restrict__ offsP,// [4][2][18][4096]
    const float* __restrict__ b_off,
    u16* __restrict__ ST)           // [8192][2304]
{
    __shared__ int4   s_ofs[576];
    __shared__ float4 s_w[576];

    const int h  = blockIdx.x;
    const int b  = blockIdx.y;
    const int cs = blockIdx.z << 7;   // 0 or 128
    const int tid = threadIdx.x;

    for (int p = tid; p < 576; p += 256) {
        const int k = p >> 6;
        const int w = p & 63;
        const size_t iy = (((size_t)(b * 18 + 2 * k)) << 12) + (h << 6) + w;
        float dy = b_off[2 * k], dx = b_off[2 * k + 1];
#pragma unroll
        for (int kz = 0; kz < 4; kz++) {
            dy += offsP[(size_t)kz * 147456 + iy];
            dx += offsP[(size_t)kz * 147456 + iy + 4096];
        }
        const float py = (float)h + (float)(k / 3 - 1) + dy;
        const float px = (float)w + (float)(k % 3 - 1) + dx;
        const float y0f = floorf(py), x0f = floorf(px);
        const int y0 = (int)y0f, x0 = (int)x0f;
        const float wy1 = py - y0f, wx1 = px - x0f;
        const float wy0 = 1.f - wy1, wx0 = 1.f - wx1;
        const int y1 = y0 + 1, x1 = x0 + 1;
        const bool vy0 = (y0 >= 0) && (y0 < 64);
        const bool vy1 = (y1 >= 0) && (y1 < 64);
        const bool vx0 = (x0 >= 0) && (x0 < 64);
        const bool vx1 = (x1 >= 0) && (x1 < 64);
        const int cy0 = min(max(y0, 0), 63), cy1 = min(max(y1, 0), 63);
        const int cx0 = min(max(x0, 0), 63), cx1 = min(max(x1, 0), 63);
        int4 o4; float4 w4;
        o4.x = (cy0 << 6) + cx0;  w4.x = wy0 * wx0 * ((vy0 && vx0) ? 1.f : 0.f);
        o4.y = (cy0 << 6) + cx1;  w4.y = wy0 * wx1 * ((vy0 && vx1) ? 1.f : 0.f);
        o4.z = (cy1 << 6) + cx0;  w4.z = wy1 * wx0 * ((vy1 && vx0) ? 1.f : 0.f);
        o4.w = (cy1 << 6) + cx1;  w4.w = wy1 * wx1 * ((vy1 && vx1) ? 1.f : 0.f);
        s_ofs[p] = o4; s_w[p] = w4;
    }
    __syncthreads();

    const int wid  = tid >> 6;
    const int lane = tid & 63;
    const int cl   = cs + lane * 2;
    const u16* base = out1T + (((size_t)b) << 12) * 256 + cl;
    for (int p = wid; p < 576; p += 4) {
        const int k = p >> 6;
        const int w = p & 63;
        const int4   o4 = s_ofs[p];
        const float4 w4 = s_w[p];
        const u32 u0 = *(const u32*)(base + (size_t)o4.x * 256);
        const u32 u1 = *(const u32*)(base + (size_t)o4.y * 256);
        const u32 u2 = *(const u32*)(base + (size_t)o4.z * 256);
        const u32 u3 = *(const u32*)(base + (size_t)o4.w * 256);
        const float f0 = w4.x * bf2f((u16)(u0 & 0xffff)) + w4.y * bf2f((u16)(u1 & 0xffff))
                       + w4.z * bf2f((u16)(u2 & 0xffff)) + w4.w * bf2f((u16)(u3 & 0xffff));
        const float f1 = w4.x * bf2f((u16)(u0 >> 16)) + w4.y * bf2f((u16)(u1 >> 16))
                       + w4.z * bf2f((u16)(u2 >> 16)) + w4.w * bf2f((u16)(u3 >> 16));
        const u32 ov = (u32)f2bf(f0) | ((u32)f2bf(f1) << 16);
        *(u32*)(ST + ((size_t)(b * 4096 + h * 64 + w)) * 2304 + k * 256 + cl) = ov;
    }
}

// ---------------------------------------------------------------------------
extern "C" void kernel_launch(void* const* d_in, const int* in_sizes, int n_in,
                              void* d_out, int out_size, void* d_ws, size_t ws_size,
                              hipStream_t stream) {
    const float* x     = (const float*)d_in[0];
    const float* w1    = (const float*)d_in[1];
    const float* g1    = (const float*)d_in[2];
    const float* b1    = (const float*)d_in[3];
    const float* m1    = (const float*)d_in[4];
    const float* v1    = (const float*)d_in[5];
    const float* w_off = (const float*)d_in[6];
    const float* b_off = (const float*)d_in[7];
    const float* w2    = (const float*)d_in[8];
    const float* g2    = (const float*)d_in[9];
    const float* b2    = (const float*)d_in[10];
    const float* m2    = (const float*)d_in[11];
    const float* v2    = (const float*)d_in[12];
    const float* w3    = (const float*)d_in[13];
    const float* g3    = (const float*)d_in[14];
    const float* b3    = (const float*)d_in[15];
    const float* m3    = (const float*)d_in[16];
    const float* v3    = (const float*)d_in[17];
    float* out = (float*)d_out;

    char* ws = (char*)d_ws;
    u16*  xbT   = (u16*)ws;   ws += (size_t)8192 * 1024 * 2;
    u16*  wb1   = (u16*)ws;   ws += (size_t)256 * 1024 * 2;
    u16*  wb3   = (u16*)ws;   ws += (size_t)1024 * 256 * 2;
    u16*  wOffP = (u16*)ws;   ws += (size_t)64 * 2304 * 2;
    u16*  wb2p  = (u16*)ws;   ws += (size_t)256 * 2304 * 2;
    u16*  zbuf  = (u16*)ws;   ws += (size_t)512 * 2;
    u16*  out1T = (u16*)ws;   ws += (size_t)8192 * 256 * 2;
    float* offsP = (float*)ws; ws += (size_t)4 * 147456 * 4;
    u16*  ST    = (u16*)ws;   ws += (size_t)8192 * 2304 * 2;
    u16*  o2T   = (u16*)ws;   ws += (size_t)8192 * 256 * 2;

    // conversions / reorgs
    cvt_w<<<dim3(256), 256, 0, stream>>>(w1, wb1, 262144 / 4);
    cvt_w<<<dim3(256), 256, 0, stream>>>(w3, wb3, 262144 / 4);
    reorg_w<<<dim3(64), 256, 0, stream>>>(w_off, wOffP, 18);
    reorg_w<<<dim3(256), 256, 0, stream>>>(w2, wb2p, 256);
    zfill<<<dim3(2), 256, 0, stream>>>(zbuf, 512);
    cvt_x_T<<<dim3(64, 16, 2), 256, 0, stream>>>(x, xbT);

    // Stage 1: conv1x1 + BN1 + ReLU -> out1T [n][256]
    gemm_bn<1><<<dim3(64, 4), 256, 12288 + 128 * 72 * 2, stream>>>(
        wb1, xbT, g1, b1, m1, v1, nullptr, out1T, 1024);

    // Stage 2: offset conv, split-K x4 -> fp32 partials
    gemm_off<<<dim3(64, 4), 256, 0, stream>>>(wOffP, out1T, zbuf, offsP);

    // Stage 3a: deformable im2col ST[n][k*256+c]
    sample_k<<<dim3(64, 2, 2), 256, 0, stream>>>(out1T, offsP, b_off, ST);

    // Stage 3b: deform GEMM + BN2 + ReLU -> o2T [n][256]
    gemm_bn<1><<<dim3(64, 4), 256, 12288 + 128 * 72 * 2, stream>>>(
        wb2p, ST, g2, b2, m2, v2, nullptr, o2T, 2304);

    // Stage 4: conv1x1 + BN3 + resid + ReLU -> fp32 out (LDS-transposed epilogue)
    gemm_bn<2><<<dim3(64, 16), 256, 12288 + 64 * 132 * 4, stream>>>(
        wb3, o2T, g3, b3, m3, v3, x, out, 256);
}

// Round 5
// 129.656 us; speedup vs baseline: 5.2331x; 1.1806x over previous
//
#include <hip/hip_runtime.h>
#include <hip/hip_bf16.h>

#define EPSV 1e-5f

typedef __attribute__((ext_vector_type(4))) float f32x4;
typedef __attribute__((ext_vector_type(8))) short bf16x8;
typedef unsigned short u16;
typedef unsigned int u32;

#define AS1(p) ((const __attribute__((address_space(1))) void*)(p))
#define AS3(p) ((__attribute__((address_space(3))) void*)(p))

__device__ __forceinline__ float bf2f(u16 u) {
    union { u32 i; float f; } x; x.i = ((u32)u) << 16; return x.f;
}
__device__ __forceinline__ u16 f2bf(float f) {
    __hip_bfloat16 h = __float2bfloat16(f);
    return *reinterpret_cast<u16*>(&h);
}

// ---------------------------------------------------------------------------
__global__ __launch_bounds__(256) void cvt_w(const float* __restrict__ in,
                                             u16* __restrict__ out, int n4) {
    int i = blockIdx.x * 256 + threadIdx.x;
    if (i < n4) {
        float4 v = ((const float4*)in)[i];
        ushort4 o;
        o.x = f2bf(v.x); o.y = f2bf(v.y); o.z = f2bf(v.z); o.w = f2bf(v.w);
        ((ushort4*)out)[i] = o;
    }
}

__global__ __launch_bounds__(256) void reorg_w(const float* __restrict__ src,
                                               u16* __restrict__ dst, int O) {
    const int o = blockIdx.x;
    const int c = threadIdx.x;
#pragma unroll
    for (int k = 0; k < 9; k++) {
        float v = (o < O) ? src[((size_t)(o * 256 + c)) * 9 + k] : 0.f;
        dst[(size_t)o * 2304 + k * 256 + c] = f2bf(v);
    }
}

__global__ __launch_bounds__(256) void zfill(u16* __restrict__ p, int n) {
    int i = blockIdx.x * 256 + threadIdx.x;
    if (i < n) p[i] = 0;
}

// ---------------------------------------------------------------------------
// x [2][1024][4096] fp32  ->  xbT [8192][1024] bf16
// ---------------------------------------------------------------------------
__global__ __launch_bounds__(256) void cvt_x_T(const float* __restrict__ x,
                                               u16* __restrict__ xbT) {
    __shared__ u16 tile[64][72];
    const int tid = threadIdx.x;
    const int hw0 = blockIdx.x << 6;
    const int c0  = blockIdx.y << 6;
    const int b   = blockIdx.z;
    const int cl  = tid >> 4;
    const int hwl = (tid & 15) << 2;
#pragma unroll
    for (int i = 0; i < 4; i++) {
        const int c = cl + i * 16;
        float4 v = *(const float4*)(x + (((size_t)(b * 1024 + c0 + c)) << 12) + hw0 + hwl);
        tile[hwl + 0][c] = f2bf(v.x);
        tile[hwl + 1][c] = f2bf(v.y);
        tile[hwl + 2][c] = f2bf(v.z);
        tile[hwl + 3][c] = f2bf(v.w);
    }
    __syncthreads();
    const int hw  = tid >> 2;
    const int seg = tid & 3;
    u16* dst = xbT + ((size_t)(b * 4096 + hw0 + hw)) * 1024 + c0 + seg * 16;
    const u16* src = &tile[hw][seg * 16];
#pragma unroll
    for (int q = 0; q < 2; q++)
        *(uint4*)(dst + q * 8) = *(const uint4*)(src + q * 8);
}

// ---------------------------------------------------------------------------
// Pipelined MFMA GEMM (64x128 tile, BK=32, 2-deep dbuf, counted vmcnt).
// LDS: A0@0 A1@4096 B0@8192 B1@16384 T@24576
// MODE 1: BN+ReLU -> bf16 outT[8192][M] (stride 256), swizzled LDS transpose
// MODE 2: BN + resid + ReLU -> fp32 out [2][M][4096]
// ---------------------------------------------------------------------------
#define MFMA8(ASP, BSP)                                                          \
    do {                                                                         \
        bf16x8 a0 = *(const bf16x8*)(ASP);                                       \
        bf16x8 a1 = *(const bf16x8*)((ASP) + 512);                               \
        bf16x8 b0 = *(const bf16x8*)(BSP);                                       \
        bf16x8 b1 = *(const bf16x8*)((BSP) + 512);                               \
        bf16x8 b2 = *(const bf16x8*)((BSP) + 1024);                              \
        bf16x8 b3 = *(const bf16x8*)((BSP) + 1536);                              \
        acc[0][0] = __builtin_amdgcn_mfma_f32_16x16x32_bf16(a0, b0, acc[0][0], 0, 0, 0); \
        acc[0][1] = __builtin_amdgcn_mfma_f32_16x16x32_bf16(a0, b1, acc[0][1], 0, 0, 0); \
        acc[0][2] = __builtin_amdgcn_mfma_f32_16x16x32_bf16(a0, b2, acc[0][2], 0, 0, 0); \
        acc[0][3] = __builtin_amdgcn_mfma_f32_16x16x32_bf16(a0, b3, acc[0][3], 0, 0, 0); \
        acc[1][0] = __builtin_amdgcn_mfma_f32_16x16x32_bf16(a1, b0, acc[1][0], 0, 0, 0); \
        acc[1][1] = __builtin_amdgcn_mfma_f32_16x16x32_bf16(a1, b1, acc[1][1], 0, 0, 0); \
        acc[1][2] = __builtin_amdgcn_mfma_f32_16x16x32_bf16(a1, b2, acc[1][2], 0, 0, 0); \
        acc[1][3] = __builtin_amdgcn_mfma_f32_16x16x32_bf16(a1, b3, acc[1][3], 0, 0, 0); \
    } while (0)

#define WAIT_BAR()                                  \
    do {                                            \
        asm volatile("s_waitcnt vmcnt(3)" ::: "memory"); \
        __builtin_amdgcn_s_barrier();               \
        __builtin_amdgcn_sched_barrier(0);          \
    } while (0)

#define POST_BAR()                                  \
    do {                                            \
        __builtin_amdgcn_s_barrier();               \
        __builtin_amdgcn_sched_barrier(0);          \
    } while (0)

template<int MODE>
__global__ __launch_bounds__(256) void gemm_bn(
    const u16* __restrict__ A, const u16* __restrict__ BT,
    const float* __restrict__ g, const float* __restrict__ bb,
    const float* __restrict__ m, const float* __restrict__ v,
    const float* __restrict__ resid, void* __restrict__ out, int K)
{
    extern __shared__ char sm[];

    const int tid  = threadIdx.x;
    const int lane = tid & 63;
    const int wid  = tid >> 6;
    const int n0 = blockIdx.x << 7;
    const int m0 = blockIdx.y << 6;
    const int wr = wid >> 1, wc = wid & 1;
    const int lr = lane & 15, kg = lane >> 4;

    f32x4 acc[2][4] = {};

    const int arow = tid >> 2, aseg = (tid & 3) << 3;
    const u16* aG  = A  + (size_t)(m0 + arow) * K + aseg;
    const u16* bG0 = BT + (size_t)(n0 + arow) * K + aseg;
    const u16* bG1 = BT + (size_t)(n0 + 64 + arow) * K + aseg;

    char* ldsA0  = sm + wid * 1024;
    char* ldsA1  = sm + 4096  + wid * 1024;
    char* ldsB00 = sm + 8192  + wid * 1024;
    char* ldsB01 = sm + 12288 + wid * 1024;
    char* ldsB10 = sm + 16384 + wid * 1024;
    char* ldsB11 = sm + 20480 + wid * 1024;

    const u16* Asp0 = (const u16*)(sm)         + (wr * 32 + lr) * 32 + kg * 8;
    const u16* Asp1 = (const u16*)(sm + 4096)  + (wr * 32 + lr) * 32 + kg * 8;
    const u16* Bsp0 = (const u16*)(sm + 8192)  + (wc * 64 + lr) * 32 + kg * 8;
    const u16* Bsp1 = (const u16*)(sm + 16384) + (wc * 64 + lr) * 32 + kg * 8;

#define ISSUE_G(LA, LB0, LB1, kt)                                                  \
    do {                                                                           \
        __builtin_amdgcn_global_load_lds(AS1(aG + (kt)),  AS3(LA),  16, 0, 0);     \
        __builtin_amdgcn_global_load_lds(AS1(bG0 + (kt)), AS3(LB0), 16, 0, 0);     \
        __builtin_amdgcn_global_load_lds(AS1(bG1 + (kt)), AS3(LB1), 16, 0, 0);     \
    } while (0)

    const int nT = K >> 5;
    ISSUE_G(ldsA0, ldsB00, ldsB01, 0);
    ISSUE_G(ldsA1, ldsB10, ldsB11, 32);

    for (int t = 0; t < nT; t += 2) {
        WAIT_BAR();
        MFMA8(Asp0, Bsp0);
        POST_BAR();
        { const int kn = (t + 2 < nT ? t + 2 : t) << 5;
          ISSUE_G(ldsA0, ldsB00, ldsB01, kn); }
        WAIT_BAR();
        MFMA8(Asp1, Bsp1);
        POST_BAR();
        { const int kn = (t + 3 < nT ? t + 3 : t + 1) << 5;
          ISSUE_G(ldsA1, ldsB10, ldsB11, kn); }
    }
#undef ISSUE_G

    float sc[2][4], tc[2][4];
#pragma unroll
    for (int mm = 0; mm < 2; mm++)
#pragma unroll
        for (int r = 0; r < 4; r++) {
            const int o = m0 + wr * 32 + mm * 16 + kg * 4 + r;
            const float s = g[o] * rsqrtf(v[o] + EPSV);
            sc[mm][r] = s;
            tc[mm][r] = bb[o] - m[o] * s;
        }

    if (MODE == 1) {
        // swizzled transpose tile: rows nl, 36 words (72 u16); word col
        // cw' = cw ^ (((nl>>3)&3)<<2) breaks the nl/nl+8 bank aliasing.
        u32* T32 = (u32*)(sm + 24576);
#pragma unroll
        for (int mm = 0; mm < 2; mm++) {
            const int ol = wr * 32 + mm * 16 + kg * 4;
            const int cw0 = ol >> 1;
#pragma unroll
            for (int j = 0; j < 4; j++) {
                const int nl = wc * 64 + j * 16 + lr;
                const int sw = (nl >> 3) & 3;
                float v0 = acc[mm][j][0] * sc[mm][0] + tc[mm][0];
                float v1 = acc[mm][j][1] * sc[mm][1] + tc[mm][1];
                float v2 = acc[mm][j][2] * sc[mm][2] + tc[mm][2];
                float v3 = acc[mm][j][3] * sc[mm][3] + tc[mm][3];
                v0 = v0 > 0.f ? v0 : 0.f; v1 = v1 > 0.f ? v1 : 0.f;
                v2 = v2 > 0.f ? v2 : 0.f; v3 = v3 > 0.f ? v3 : 0.f;
                uint2 pw;
                pw.x = (u32)f2bf(v0) | ((u32)f2bf(v1) << 16);
                pw.y = (u32)f2bf(v2) | ((u32)f2bf(v3) << 16);
                *(uint2*)&T32[nl * 36 + (cw0 ^ (sw << 2))] = pw;
            }
        }
        __syncthreads();
        const int nl = tid >> 1, half = tid & 1;
        const int sw = (nl >> 3) & 3;
        u16* dst = (u16*)out + (size_t)(n0 + nl) * 256 + m0 + half * 32;
#pragma unroll
        for (int q = 0; q < 4; q++) {
            uint4 val = *(const uint4*)&T32[nl * 36 + ((half * 16 + q * 4) ^ (sw << 2))];
            *(uint4*)(dst + q * 8) = val;
        }
    } else {
        float* T = (float*)(sm + 24576);   // [64][132]
#pragma unroll
        for (int mm = 0; mm < 2; mm++) {
            const int ol = wr * 32 + mm * 16 + kg * 4;
#pragma unroll
            for (int j = 0; j < 4; j++) {
                const int nl = wc * 64 + j * 16 + lr;
#pragma unroll
                for (int r = 0; r < 4; r++)
                    T[(ol + r) * 132 + nl] = acc[mm][j][r] * sc[mm][r] + tc[mm][r];
            }
        }
        __syncthreads();
        float* O = (float*)out;
        for (int idx = tid; idx < 2048; idx += 256) {
            const int ol  = idx >> 5;
            const int nl4 = (idx & 31) << 2;
            const int n = n0 + nl4;
            const size_t gidx = ((size_t)(n >> 12) << 22) + ((size_t)(m0 + ol) << 12) + (n & 4095);
            float4 rv = *(const float4*)(resid + gidx);
            float4 ov;
            ov.x = T[ol * 132 + nl4 + 0] + rv.x;
            ov.y = T[ol * 132 + nl4 + 1] + rv.y;
            ov.z = T[ol * 132 + nl4 + 2] + rv.z;
            ov.w = T[ol * 132 + nl4 + 3] + rv.w;
            ov.x = ov.x > 0.f ? ov.x : 0.f;
            ov.y = ov.y > 0.f ? ov.y : 0.f;
            ov.z = ov.z > 0.f ? ov.z : 0.f;
            ov.w = ov.w > 0.f ? ov.w : 0.f;
            *(float4*)(O + gidx) = ov;
        }
    }
}

// ---------------------------------------------------------------------------
// Offset conv: split-K implicit-im2col MFMA GEMM, same 2-deep pipeline.
// ---------------------------------------------------------------------------
__global__ __launch_bounds__(256) void gemm_off(
    const u16* __restrict__ A,      // [64][2304] (rows >=18 zero)
    const u16* __restrict__ out1T,  // [8192][256]
    const u16* __restrict__ zbuf,
    float* __restrict__ offsP)      // [4][2][18][4096]
{
    __shared__ char sm[24576];

    const int tid  = threadIdx.x;
    const int lane = tid & 63;
    const int wid  = tid >> 6;
    const int n0 = blockIdx.x << 7;
    const int kz = blockIdx.y;
    const int wr = wid >> 1, wc = wid & 1;
    const int lr = lane & 15, kg = lane >> 4;

    f32x4 acc[2][4] = {};

    const int arow = tid >> 2, aseg = (tid & 3) << 3;
    const u16* aG = A + (size_t)arow * 2304 + aseg;
    const int nB0 = n0 + arow, nB1 = n0 + 64 + arow;
    const int y0r = (nB0 & 4095) >> 6, x0r = nB0 & 63;
    const int y1r = (nB1 & 4095) >> 6, x1r = nB1 & 63;

    char* ldsA0  = sm + wid * 1024;
    char* ldsA1  = sm + 4096  + wid * 1024;
    char* ldsB00 = sm + 8192  + wid * 1024;
    char* ldsB01 = sm + 12288 + wid * 1024;
    char* ldsB10 = sm + 16384 + wid * 1024;
    char* ldsB11 = sm + 20480 + wid * 1024;

    const u16* Asp0 = (const u16*)(sm)         + (wr * 32 + lr) * 32 + kg * 8;
    const u16* Asp1 = (const u16*)(sm + 4096)  + (wr * 32 + lr) * 32 + kg * 8;
    const u16* Bsp0 = (const u16*)(sm + 8192)  + (wc * 64 + lr) * 32 + kg * 8;
    const u16* Bsp1 = (const u16*)(sm + 16384) + (wc * 64 + lr) * 32 + kg * 8;

#define ISSUE_O(LA, LB0, LB1, kt)                                                  \
    do {                                                                           \
        const int tap = (kt) >> 8, c0 = (kt) & 255;                                \
        const int dy = tap / 3 - 1, dx = tap % 3 - 1;                              \
        const int sh = dy * 64 + dx;                                               \
        const bool vv0 = ((unsigned)(y0r + dy) < 64u) && ((unsigned)(x0r + dx) < 64u); \
        const bool vv1 = ((unsigned)(y1r + dy) < 64u) && ((unsigned)(x1r + dx) < 64u); \
        const u16* s0 = vv0 ? out1T + (size_t)(nB0 + sh) * 256 + c0 + aseg : zbuf + aseg; \
        const u16* s1 = vv1 ? out1T + (size_t)(nB1 + sh) * 256 + c0 + aseg : zbuf + aseg; \
        __builtin_amdgcn_global_load_lds(AS1(aG + (kt)), AS3(LA),  16, 0, 0);      \
        __builtin_amdgcn_global_load_lds(AS1(s0),        AS3(LB0), 16, 0, 0);      \
        __builtin_amdgcn_global_load_lds(AS1(s1),        AS3(LB1), 16, 0, 0);      \
    } while (0)

    const int kBase = kz * 576;
    ISSUE_O(ldsA0, ldsB00, ldsB01, kBase);
    ISSUE_O(ldsA1, ldsB10, ldsB11, kBase + 32);

    for (int t = 0; t < 18; t += 2) {
        WAIT_BAR();
        MFMA8(Asp0, Bsp0);
        POST_BAR();
        { const int kn = kBase + ((t + 2 < 18 ? t + 2 : t) << 5);
          ISSUE_O(ldsA0, ldsB00, ldsB01, kn); }
        WAIT_BAR();
        MFMA8(Asp1, Bsp1);
        POST_BAR();
        { const int kn = kBase + ((t + 3 < 18 ? t + 3 : t + 1) << 5);
          ISSUE_O(ldsA1, ldsB10, ldsB11, kn); }
    }
#undef ISSUE_O

#pragma unroll
    for (int mm = 0; mm < 2; mm++)
#pragma unroll
        for (int r = 0; r < 4; r++) {
            const int o = wr * 32 + mm * 16 + kg * 4 + r;
            if (o < 18) {
#pragma unroll
                for (int j = 0; j < 4; j++) {
                    const int n = n0 + wc * 64 + j * 16 + lr;
                    offsP[(size_t)kz * 147456 +
                          (((size_t)((n >> 12) * 18 + o)) << 12) + (n & 4095)] =
                        acc[mm][j][r];
                }
            }
        }
}

// ---------------------------------------------------------------------------
// Deformable im2col: one wave per sample point, lanes = 128 channels.
// ---------------------------------------------------------------------------
__global__ __launch_bounds__(256) void sample_k(
    const u16* __restrict__ out1T,  // [8192][256]
    const float* __restrict__ offsP,// [4][2][18][4096]
    const float* __restrict__ b_off,
    u16* __restrict__ ST)           // [8192][2304]
{
    __shared__ int4   s_ofs[576];
    __shared__ float4 s_w[576];

    const int h  = blockIdx.x;
    const int b  = blockIdx.y;
    const int cs = blockIdx.z << 7;
    const int tid = threadIdx.x;

    for (int p = tid; p < 576; p += 256) {
        const int k = p >> 6;
        const int w = p & 63;
        const size_t iy = (((size_t)(b * 18 + 2 * k)) << 12) + (h << 6) + w;
        float dy = b_off[2 * k], dx = b_off[2 * k + 1];
#pragma unroll
        for (int kzz = 0; kzz < 4; kzz++) {
            dy += offsP[(size_t)kzz * 147456 + iy];
            dx += offsP[(size_t)kzz * 147456 + iy + 4096];
        }
        const float py = (float)h + (float)(k / 3 - 1) + dy;
        const float px = (float)w + (float)(k % 3 - 1) + dx;
        const float y0f = floorf(py), x0f = floorf(px);
        const int y0 = (int)y0f, x0 = (int)x0f;
        const float wy1 = py - y0f, wx1 = px - x0f;
        const float wy0 = 1.f - wy1, wx0 = 1.f - wx1;
        const int y1 = y0 + 1, x1 = x0 + 1;
        const bool vy0 = (y0 >= 0) && (y0 < 64);
        const bool vy1 = (y1 >= 0) && (y1 < 64);
        const bool vx0 = (x0 >= 0) && (x0 < 64);
        const bool vx1 = (x1 >= 0) && (x1 < 64);
        const int cy0 = min(max(y0, 0), 63), cy1 = min(max(y1, 0), 63);
        const int cx0 = min(max(x0, 0), 63), cx1 = min(max(x1, 0), 63);
        int4 o4; float4 w4;
        o4.x = (cy0 << 6) + cx0;  w4.x = wy0 * wx0 * ((vy0 && vx0) ? 1.f : 0.f);
        o4.y = (cy0 << 6) + cx1;  w4.y = wy0 * wx1 * ((vy0 && vx1) ? 1.f : 0.f);
        o4.z = (cy1 << 6) + cx0;  w4.z = wy1 * wx0 * ((vy1 && vx0) ? 1.f : 0.f);
        o4.w = (cy1 << 6) + cx1;  w4.w = wy1 * wx1 * ((vy1 && vx1) ? 1.f : 0.f);
        s_ofs[p] = o4; s_w[p] = w4;
    }
    __syncthreads();

    const int wv   = tid >> 6;
    const int lane = tid & 63;
    const int cl   = cs + lane * 2;
    const u16* base = out1T + (((size_t)b) << 12) * 256 + cl;
    for (int p = wv; p < 576; p += 4) {
        const int k = p >> 6;
        const int w = p & 63;
        const int4   o4 = s_ofs[p];
        const float4 w4 = s_w[p];
        const u32 u0 = *(const u32*)(base + (size_t)o4.x * 256);
        const u32 u1 = *(const u32*)(base + (size_t)o4.y * 256);
        const u32 u2 = *(const u32*)(base + (size_t)o4.z * 256);
        const u32 u3 = *(const u32*)(base + (size_t)o4.w * 256);
        const float f0 = w4.x * bf2f((u16)(u0 & 0xffff)) + w4.y * bf2f((u16)(u1 & 0xffff))
                       + w4.z * bf2f((u16)(u2 & 0xffff)) + w4.w * bf2f((u16)(u3 & 0xffff));
        const float f1 = w4.x * bf2f((u16)(u0 >> 16)) + w4.y * bf2f((u16)(u1 >> 16))
                       + w4.z * bf2f((u16)(u2 >> 16)) + w4.w * bf2f((u16)(u3 >> 16));
        const u32 ov = (u32)f2bf(f0) | ((u32)f2bf(f1) << 16);
        *(u32*)(ST + ((size_t)(b * 4096 + h * 64 + w)) * 2304 + k * 256 + cl) = ov;
    }
}

// ---------------------------------------------------------------------------
extern "C" void kernel_launch(void* const* d_in, const int* in_sizes, int n_in,
                              void* d_out, int out_size, void* d_ws, size_t ws_size,
                              hipStream_t stream) {
    const float* x     = (const float*)d_in[0];
    const float* w1    = (const float*)d_in[1];
    const float* g1    = (const float*)d_in[2];
    const float* b1    = (const float*)d_in[3];
    const float* m1    = (const float*)d_in[4];
    const float* v1    = (const float*)d_in[5];
    const float* w_off = (const float*)d_in[6];
    const float* b_off = (const float*)d_in[7];
    const float* w2    = (const float*)d_in[8];
    const float* g2    = (const float*)d_in[9];
    const float* b2    = (const float*)d_in[10];
    const float* m2    = (const float*)d_in[11];
    const float* v2    = (const float*)d_in[12];
    const float* w3    = (const float*)d_in[13];
    const float* g3    = (const float*)d_in[14];
    const float* b3    = (const float*)d_in[15];
    const float* m3    = (const float*)d_in[16];
    const float* v3    = (const float*)d_in[17];
    float* out = (float*)d_out;

    char* ws = (char*)d_ws;
    u16*  xbT   = (u16*)ws;   ws += (size_t)8192 * 1024 * 2;
    u16*  wb1   = (u16*)ws;   ws += (size_t)256 * 1024 * 2;
    u16*  wb3   = (u16*)ws;   ws += (size_t)1024 * 256 * 2;
    u16*  wOffP = (u16*)ws;   ws += (size_t)64 * 2304 * 2;
    u16*  wb2p  = (u16*)ws;   ws += (size_t)256 * 2304 * 2;
    u16*  zbuf  = (u16*)ws;   ws += (size_t)512 * 2;
    u16*  out1T = (u16*)ws;   ws += (size_t)8192 * 256 * 2;
    float* offsP = (float*)ws; ws += (size_t)4 * 147456 * 4;
    u16*  ST    = (u16*)ws;   ws += (size_t)8192 * 2304 * 2;
    u16*  o2T   = (u16*)ws;   ws += (size_t)8192 * 256 * 2;

    cvt_w<<<dim3(256), 256, 0, stream>>>(w1, wb1, 262144 / 4);
    cvt_w<<<dim3(256), 256, 0, stream>>>(w3, wb3, 262144 / 4);
    reorg_w<<<dim3(64), 256, 0, stream>>>(w_off, wOffP, 18);
    reorg_w<<<dim3(256), 256, 0, stream>>>(w2, wb2p, 256);
    zfill<<<dim3(2), 256, 0, stream>>>(zbuf, 512);
    cvt_x_T<<<dim3(64, 16, 2), 256, 0, stream>>>(x, xbT);

    // Stage 1: conv1x1 + BN1 + ReLU -> out1T [n][256]
    gemm_bn<1><<<dim3(64, 4), 256, 24576 + 18432, stream>>>(
        wb1, xbT, g1, b1, m1, v1, nullptr, out1T, 1024);

    // Stage 2: offset conv, split-K x4 -> fp32 partials
    gemm_off<<<dim3(64, 4), 256, 0, stream>>>(wOffP, out1T, zbuf, offsP);

    // Stage 3a: deformable im2col ST[n][k*256+c]
    sample_k<<<dim3(64, 2, 2), 256, 0, stream>>>(out1T, offsP, b_off, ST);

    // Stage 3b: deform GEMM + BN2 + ReLU -> o2T [n][256]
    gemm_bn<1><<<dim3(64, 4), 256, 24576 + 18432, stream>>>(
        wb2p, ST, g2, b2, m2, v2, nullptr, o2T, 2304);

    // Stage 4: conv1x1 + BN3 + resid + ReLU -> fp32 out
    gemm_bn<2><<<dim3(64, 16), 256, 24576 + 33792, stream>>>(
        wb3, o2T, g3, b3, m3, v3, x, out, 256);
}